// Round 11
// baseline (172.596 us; speedup 1.0000x reference)
//
#include <hip/hip_runtime.h>
#include <hip/hip_bf16.h>
#include <cstdint>
#include <cstddef>

#define B_  2
#define T_  2048
#define D_  1024
#define H_  16
#define M_  (B_*T_)   // 4096 rows total

typedef __bf16 bf16_t;
typedef __attribute__((ext_vector_type(8))) __bf16 bf16x8;
typedef __attribute__((ext_vector_type(4))) __bf16 bf16x4;
typedef __attribute__((ext_vector_type(4))) float f32x4;
typedef __attribute__((ext_vector_type(16))) float f32x16;
typedef unsigned int u32;
typedef __attribute__((ext_vector_type(4))) u32 u32x4;

#define MFMA16(a,b,c) __builtin_amdgcn_mfma_f32_16x16x32_bf16(a,b,c,0,0,0)
#define MFMA32(a,b,c) __builtin_amdgcn_mfma_f32_32x32x16_bf16(a,b,c,0,0,0)
#define EXP2(x) __builtin_amdgcn_exp2f(x)

// 0.125 * log2(e): folds 1/sqrt(DH) and the e->2 base change into Wq
#define QSCALE 0.18033688011112042f
// defer-max threshold in log2 domain: skip O-rescale while P <= 2^10
#define DEFER_THR 10.0f

__device__ inline void async16(const void* g, void* l) {
  __builtin_amdgcn_global_load_lds((const __attribute__((address_space(1))) void*)g,
                                   (__attribute__((address_space(3))) void*)l, 16, 0, 0);
}

__device__ __forceinline__ f32x16 zero16() {
  f32x16 z;
  #pragma unroll
  for (int i = 0; i < 16; ++i) z[i] = 0.f;
  return z;
}

// pack two f32 -> one u32 of 2 bf16 (compiler fuses to v_cvt_pk_bf16_f32)
__device__ __forceinline__ u32 pk2(float lo, float hi) {
  u32 a = __builtin_bit_cast(unsigned short, (__bf16)lo);
  u32 b = __builtin_bit_cast(unsigned short, (__bf16)hi);
  return a | (b << 16);
}
// lane^32 exchange via shfl (ds_bpermute) — semantics proven good (r4/r5).
// NOTE: __builtin_amdgcn_permlane32_swap(u,u) is NOT usable: r3/r6 failures.
__device__ __forceinline__ float xswap_max(float x) {
  return fmaxf(x, __shfl_xor(x, 32));
}
__device__ __forceinline__ float xswap_sum(float x) {
  return x + __shfl_xor(x, 32);
}

// ---------------- cast kernels ----------------
__global__ __launch_bounds__(256) void cast_x_k(const float* __restrict__ in,
                                                bf16_t* __restrict__ out, int n8) {
  int i = blockIdx.x * 256 + threadIdx.x;
  if (i >= n8) return;
  const float4* p = (const float4*)in + 2 * (size_t)i;
  float4 a = p[0], b = p[1];
  bf16x8 r = { (__bf16)a.x, (__bf16)a.y, (__bf16)a.z, (__bf16)a.w,
               (__bf16)b.x, (__bf16)b.y, (__bf16)b.z, (__bf16)b.w };
  *((bf16x8*)out + i) = r;
}

__global__ __launch_bounds__(256) void cast_w_k(const float* __restrict__ wq,
                                                const float* __restrict__ wk,
                                                const float* __restrict__ wv,
                                                const float* __restrict__ wo,
                                                bf16_t* __restrict__ outbase) {
  const float* src = blockIdx.y == 0 ? wq : blockIdx.y == 1 ? wk : blockIdx.y == 2 ? wv : wo;
  const float sc = (blockIdx.y == 0) ? QSCALE : 1.0f;
  bf16_t* out = outbase + (size_t)blockIdx.y * D_ * D_;
  int i = blockIdx.x * 256 + threadIdx.x;
  const float4* p = (const float4*)src + 2 * (size_t)i;
  float4 a = p[0], b = p[1];
  bf16x8 r = { (__bf16)(a.x*sc), (__bf16)(a.y*sc), (__bf16)(a.z*sc), (__bf16)(a.w*sc),
               (__bf16)(b.x*sc), (__bf16)(b.y*sc), (__bf16)(b.z*sc), (__bf16)(b.w*sc) };
  *((bf16x8*)out + i) = r;
}

// ---------------- 128x128 NT GEMM core (C = A * W^T) ----------------
template<typename OUT>
__device__ __forceinline__ void gemm_bt_128(const bf16_t* __restrict__ A,
                                            const bf16_t* __restrict__ W,
                                            OUT* __restrict__ C,
                                            int Kdim, int ldc_n, int brow, int bcol) {
  __shared__ __align__(16) bf16_t As[128 * 32];
  __shared__ __align__(16) bf16_t Bs[128 * 32];
  const int lane = threadIdx.x & 63;
  const int w    = threadIdx.x >> 6;
  const int lo   = lane & 15, hi = lane >> 4;
  const int wr   = w >> 1, wc = w & 1;

  f32x4 acc[4][4];
  #pragma unroll
  for (int i = 0; i < 4; ++i)
    #pragma unroll
    for (int j = 0; j < 4; ++j) acc[i][j] = (f32x4){0.f, 0.f, 0.f, 0.f};

  for (int kt = 0; kt < Kdim; kt += 32) {
    #pragma unroll
    for (int i = 0; i < 2; ++i) {
      int chunk = w * 2 + i;
      int r = chunk * 16 + (lane >> 2);
      int c = (lane & 3) * 8;
      async16(A + (size_t)(brow + r) * Kdim + kt + c, (char*)As + chunk * 1024);
      async16(W + (size_t)(bcol + r) * Kdim + kt + c, (char*)Bs + chunk * 1024);
    }
    __syncthreads();
    bf16x8 af[4], bfr[4];
    #pragma unroll
    for (int mi = 0; mi < 4; ++mi)
      af[mi] = *(const bf16x8*)&As[(wr * 64 + mi * 16 + lo) * 32 + hi * 8];
    #pragma unroll
    for (int ni = 0; ni < 4; ++ni)
      bfr[ni] = *(const bf16x8*)&Bs[(wc * 64 + ni * 16 + lo) * 32 + hi * 8];
    #pragma unroll
    for (int mi = 0; mi < 4; ++mi)
      #pragma unroll
      for (int ni = 0; ni < 4; ++ni)
        acc[mi][ni] = MFMA16(af[mi], bfr[ni], acc[mi][ni]);
    __syncthreads();
  }

  #pragma unroll
  for (int mi = 0; mi < 4; ++mi)
    #pragma unroll
    for (int ni = 0; ni < 4; ++ni)
      #pragma unroll
      for (int i = 0; i < 4; ++i) {
        int row = brow + wr * 64 + mi * 16 + hi * 4 + i;
        int col = bcol + wc * 64 + ni * 16 + lo;
        C[(size_t)row * ldc_n + col] = (OUT)acc[mi][ni][i];
      }
}

__global__ __launch_bounds__(256) void qkv_gemm_k(const bf16_t* __restrict__ xb,
                                                  const bf16_t* __restrict__ wqb,
                                                  const bf16_t* __restrict__ wkb,
                                                  const bf16_t* __restrict__ wvb,
                                                  bf16_t* __restrict__ Q,
                                                  bf16_t* __restrict__ K,
                                                  bf16_t* __restrict__ V) {
  const bf16_t* W = blockIdx.z == 0 ? wqb : blockIdx.z == 1 ? wkb : wvb;
  bf16_t* C       = blockIdx.z == 0 ? Q   : blockIdx.z == 1 ? K   : V;
  gemm_bt_128<bf16_t>(xb, W, C, D_, D_, blockIdx.y * 128, blockIdx.x * 128);
}

__global__ __launch_bounds__(256) void out_gemm_k(const bf16_t* __restrict__ O,
                                                  const bf16_t* __restrict__ wob,
                                                  float* __restrict__ Y) {
  gemm_bt_128<float>(O, wob, Y, D_, D_, blockIdx.y * 128, blockIdx.x * 128);
}

// ---------------- V transpose: V(B,T,D) -> Vt[(b*H+h)*64+dh][T] ----------------
__global__ __launch_bounds__(256) void vt_k(const bf16_t* __restrict__ V,
                                            bf16_t* __restrict__ Vt) {
  __shared__ bf16_t Tl[64][68];
  const int t0 = blockIdx.x * 64;
  const int bh = blockIdx.y, b = bh >> 4, h = bh & 15;
  const int tid = threadIdx.x;
  #pragma unroll
  for (int it = 0; it < 2; ++it) {
    int idx = it * 256 + tid;
    int r = idx >> 3, c8 = (idx & 7) * 8;
    *(bf16x8*)&Tl[r][c8] = *(const bf16x8*)&V[((size_t)(b * T_ + t0 + r)) * D_ + h * 64 + c8];
  }
  __syncthreads();
  #pragma unroll
  for (int it = 0; it < 2; ++it) {
    int idx = it * 256 + tid;
    int dh = idx >> 3, tc = (idx & 7) * 8;
    bf16x8 v;
    #pragma unroll
    for (int j = 0; j < 8; ++j) v[j] = Tl[tc + j][dh];
    *(bf16x8*)&Vt[((size_t)bh * 64 + dh) * T_ + t0 + tc] = v;
  }
}

// ---------------- flash attention: 4-wave blocks, 5 blocks/CU ----------------
// Block = 256 threads = 4 waves; ONE q-tile (128 rows, 32/wave); one 64-row KV
// tile per iteration, double-buffered (LDS 32KB -> 5 blocks/CU). Five
// independent blocks per CU at different phases hide each other's stage/barrier
// stalls (r10 lesson: co-residency is the latency-hiding mechanism).
// tau-trick: QK^T A-rows permuted so PV B-fragment = own regs (no shuffles).
// Grid (B*H, 16), qt = 15-y: big blocks dispatch first; flat%8 = bh%8 keeps
// each head's KV on one XCD (L2-resident, r8-verified FETCH 72->12MB).
__global__ __launch_bounds__(256, 5) void attn_k(const bf16_t* __restrict__ Q,
                                                 const bf16_t* __restrict__ K,
                                                 const bf16_t* __restrict__ Vt,
                                                 bf16_t* __restrict__ O) {
  const int bh = blockIdx.x, b = bh >> 4, h = bh & 15;
  const int qt = 15 - (int)blockIdx.y;
  const int tid = threadIdx.x;

  __shared__ __align__(16) char smem[32768];   // [2 buf][K 8KB | V 8KB]

  const bf16_t* Kt0 = K + ((size_t)b * T_) * D_ + h * 64;
  const bf16_t* Vt0 = Vt + (size_t)bh * 64 * T_;

  const int lane = tid & 63, wl = tid >> 6;
  const int ln = lane & 31, hi = lane >> 5;
  // tau: swap quads 1<->2 within each 16 (involution)
  const int tau = (ln & ~12) | (((ln & 4) << 1) | ((ln & 8) >> 1));

  const int q_abs = qt * 128 + wl * 32 + ln;
  bf16x8 qf[4];
  {
    const bf16_t* Qrow = Q + ((size_t)b * T_ + q_abs) * D_ + h * 64;
    #pragma unroll
    for (int ks = 0; ks < 4; ++ks)
      qf[ks] = *(const bf16x8*)(Qrow + ks * 16 + hi * 8);
  }

  f32x16 o0 = zero16(), o1 = zero16();   // O^T: rows=dh (0..31 / 32..63), col=q=ln
  float m = -1e30f, l = 0.f;

  const int jc = 2 * qt + 2;             // KV tiles for this q-tile
  const int jd = 2 * qt + (wl >> 1);     // my wave's diagonal KV tile

#define STAGE4(BUF, TT)                                                       \
  {                                                                           \
    char* kd = smem + (BUF) * 16384;                                          \
    char* vd = smem + (BUF) * 16384 + 8192;                                   \
    _Pragma("unroll")                                                         \
    for (int it = 0; it < 2; ++it) {                                          \
      int c = it * 256 + tid;                                                 \
      int row = c >> 3, sl = c & 7;                                           \
      int slg = sl ^ (row & 7);                                               \
      async16(Kt0 + ((size_t)((TT) * 64 + row)) * D_ + slg * 8, kd + c * 16); \
      async16(Vt0 + (size_t)row * T_ + (TT) * 64 + slg * 8, vd + c * 16);     \
    }                                                                         \
  }

  // P regs are already in fragment order (tau-trick): 4 pk2, no shuffles.
#define PACK_PV4(PS, KS, VB)                                                  \
  {                                                                           \
    const int r0 = ((KS) & 1) * 8;                                            \
    u32x4 pw = {pk2((PS)[r0 + 0], (PS)[r0 + 1]),                              \
                pk2((PS)[r0 + 2], (PS)[r0 + 3]),                              \
                pk2((PS)[r0 + 4], (PS)[r0 + 5]),                              \
                pk2((PS)[r0 + 6], (PS)[r0 + 7])};                             \
    bf16x8 pb = __builtin_bit_cast(bf16x8, pw);                               \
    const int sg = (KS) * 2 + hi;                                             \
    int row = ln;                                                             \
    bf16x8 vf0 = *(const bf16x8*)((VB) + row * 64 + ((sg ^ (row & 7)) * 8));  \
    o0 = MFMA32(vf0, pb, o0);                                                 \
    row = 32 + ln;                                                            \
    bf16x8 vf1 = *(const bf16x8*)((VB) + row * 64 + ((sg ^ (row & 7)) * 8));  \
    o1 = MFMA32(vf1, pb, o1);                                                 \
  }

  STAGE4(0, 0)
  int cur = 0;
  for (int j = 0; j < jc; ++j) {
    if (j + 1 < jc) {
      STAGE4(cur ^ 1, j + 1)
      asm volatile("s_waitcnt vmcnt(4)" ::: "memory");
    } else {
      asm volatile("s_waitcnt vmcnt(0)" ::: "memory");
    }
    __builtin_amdgcn_s_barrier();

    if (j <= jd) {
      const bf16_t* Kb = (const bf16_t*)(smem + cur * 16384);
      const bf16_t* Vb = (const bf16_t*)(smem + cur * 16384 + 8192);
      // S^T = K . Q^T with tau-permuted A rows: reg r holds P at
      // kv = (r&7) + 16*(r>>3) + 8*hi  (+32 for s1)
      f32x16 s0 = zero16(), s1 = zero16();
      __builtin_amdgcn_s_setprio(1);
      #pragma unroll
      for (int ks = 0; ks < 4; ++ks) {
        const int sg = ks * 2 + hi;
        int row = tau;
        bf16x8 kf0 = *(const bf16x8*)(Kb + row * 64 + ((sg ^ (row & 7)) * 8));
        s0 = MFMA32(kf0, qf[ks], s0);
        row = 32 + tau;
        bf16x8 kf1 = *(const bf16x8*)(Kb + row * 64 + ((sg ^ (row & 7)) * 8));
        s1 = MFMA32(kf1, qf[ks], s1);
      }
      __builtin_amdgcn_s_setprio(0);
      if (j == jd) {
        const int kv0 = j * 64;
        #pragma unroll
        for (int r = 0; r < 16; ++r) {
          const int pos = (r & 7) + 16 * (r >> 3) + 8 * hi;
          if (kv0 + pos      > q_abs) s0[r] = -3e38f;
          if (kv0 + 32 + pos > q_abs) s1[r] = -3e38f;
        }
      }
      // online softmax (log2 domain), tree reductions, defer-max
      float t[16];
      #pragma unroll
      for (int r = 0; r < 16; ++r) t[r] = fmaxf(s0[r], s1[r]);
      #pragma unroll
      for (int st = 8; st >= 1; st >>= 1)
        #pragma unroll
        for (int i = 0; i < st; ++i) t[i] = fmaxf(t[i], t[i + st]);
      float pmax = xswap_max(t[0]);
      if (!__all(pmax - m <= DEFER_THR)) {
        float mn   = fmaxf(m, pmax);
        float corr = EXP2(m - mn);
        m = mn;
        l *= corr;
        #pragma unroll
        for (int r = 0; r < 16; ++r) { o0[r] *= corr; o1[r] *= corr; }
      }
      float u[16];
      #pragma unroll
      for (int r = 0; r < 16; ++r) {
        float p0 = EXP2(s0[r] - m); s0[r] = p0;
        float p1 = EXP2(s1[r] - m); s1[r] = p1;
        u[r] = p0 + p1;
      }
      #pragma unroll
      for (int st = 8; st >= 1; st >>= 1)
        #pragma unroll
        for (int i = 0; i < st; ++i) u[i] += u[i + st];
      l += xswap_sum(u[0]);
      __builtin_amdgcn_s_setprio(1);
      PACK_PV4(s0, 0, Vb)
      PACK_PV4(s0, 1, Vb)
      PACK_PV4(s1, 2, Vb)
      PACK_PV4(s1, 3, Vb)
      __builtin_amdgcn_s_setprio(0);
    }
    __builtin_amdgcn_s_barrier();
    cur ^= 1;
  }

  // epilogue: lane owns q row q_abs; o0/o1 rows are dh
  {
    float rl = 1.0f / l;
    bf16_t* Orow = O + ((size_t)b * T_ + q_abs) * D_ + h * 64;
    #pragma unroll
    for (int g = 0; g < 4; ++g) {
      const int dh0 = 8 * g + 4 * hi;
      bf16x4 v0, v1;
      #pragma unroll
      for (int jj = 0; jj < 4; ++jj) {
        v0[jj] = (__bf16)(o0[4 * g + jj] * rl);
        v1[jj] = (__bf16)(o1[4 * g + jj] * rl);
      }
      *(bf16x4*)(Orow + dh0)      = v0;
      *(bf16x4*)(Orow + 32 + dh0) = v1;
    }
  }
#undef STAGE4
#undef PACK_PV4
}

// ---------------- launcher ----------------
extern "C" void kernel_launch(void* const* d_in, const int* in_sizes, int n_in,
                              void* d_out, int out_size, void* d_ws, size_t ws_size,
                              hipStream_t stream) {
  const float* x  = (const float*)d_in[0];
  const float* wq = (const float*)d_in[1];
  const float* wk = (const float*)d_in[2];
  const float* wv = (const float*)d_in[3];
  const float* wo = (const float*)d_in[4];
  float* out = (float*)d_out;

  char* ws = (char*)d_ws;
  bf16_t* xb  = (bf16_t*)(ws);                       // 8 MB
  bf16_t* wqb = (bf16_t*)(ws + (size_t)( 8 << 20));  // 2 MB each
  bf16_t* wkb = (bf16_t*)(ws + (size_t)(10 << 20));
  bf16_t* wvb = (bf16_t*)(ws + (size_t)(12 << 20));
  bf16_t* wob = (bf16_t*)(ws + (size_t)(14 << 20));
  bf16_t* Qb  = (bf16_t*)(ws + (size_t)(16 << 20));  // 8 MB
  bf16_t* Kb  = (bf16_t*)(ws + (size_t)(24 << 20));  // 8 MB
  bf16_t* Vb  = (bf16_t*)(ws + (size_t)(32 << 20));  // 8 MB
  bf16_t* Vtb = (bf16_t*)(ws + (size_t)(40 << 20));  // 8 MB
  bf16_t* Ob  = Vb;   // Vb dead after vt_k; attn output reuses its slot

  (void)in_sizes; (void)n_in; (void)out_size; (void)ws_size;

  cast_x_k<<<dim3(M_ * D_ / 8 / 256), 256, 0, stream>>>(x, xb, M_ * D_ / 8);
  cast_w_k<<<dim3(D_ * D_ / 8 / 256, 4), 256, 0, stream>>>(wq, wk, wv, wo, wqb);
  qkv_gemm_k<<<dim3(D_ / 128, M_ / 128, 3), 256, 0, stream>>>(xb, wqb, wkb, wvb, Qb, Kb, Vb);
  vt_k<<<dim3(T_ / 64, B_ * H_), 256, 0, stream>>>(Vb, Vtb);
  attn_k<<<dim3(B_ * H_, T_ / 128), 256, 0, stream>>>(Qb, Kb, Vtb, Ob);
  out_gemm_k<<<dim3(D_ / 128, M_ / 128), 256, 0, stream>>>(Ob, wob, out);
}

// Round 12
// 126.133 us; speedup vs baseline: 1.3684x; 1.3684x over previous
//
#include <hip/hip_runtime.h>
#include <hip/hip_bf16.h>
#include <cstdint>
#include <cstddef>

#define B_  2
#define T_  2048
#define D_  1024
#define H_  16
#define M_  (B_*T_)   // 4096 rows total

typedef __bf16 bf16_t;
typedef __attribute__((ext_vector_type(8))) __bf16 bf16x8;
typedef __attribute__((ext_vector_type(4))) __bf16 bf16x4;
typedef __attribute__((ext_vector_type(4))) float f32x4;
typedef __attribute__((ext_vector_type(16))) float f32x16;
typedef unsigned int u32;
typedef __attribute__((ext_vector_type(4))) u32 u32x4;

#define MFMA16(a,b,c) __builtin_amdgcn_mfma_f32_16x16x32_bf16(a,b,c,0,0,0)
#define MFMA32(a,b,c) __builtin_amdgcn_mfma_f32_32x32x16_bf16(a,b,c,0,0,0)
#define EXP2(x) __builtin_amdgcn_exp2f(x)

// 0.125 * log2(e): folds 1/sqrt(DH) and the e->2 base change into Wq
#define QSCALE 0.18033688011112042f
// defer-max threshold in log2 domain: skip O-rescale while P <= 2^10
#define DEFER_THR 10.0f

__device__ inline void async16(const void* g, void* l) {
  __builtin_amdgcn_global_load_lds((const __attribute__((address_space(1))) void*)g,
                                   (__attribute__((address_space(3))) void*)l, 16, 0, 0);
}

__device__ __forceinline__ f32x16 zero16() {
  f32x16 z;
  #pragma unroll
  for (int i = 0; i < 16; ++i) z[i] = 0.f;
  return z;
}

// pack two f32 -> one u32 of 2 bf16 (compiler fuses to v_cvt_pk_bf16_f32)
__device__ __forceinline__ u32 pk2(float lo, float hi) {
  u32 a = __builtin_bit_cast(unsigned short, (__bf16)lo);
  u32 b = __builtin_bit_cast(unsigned short, (__bf16)hi);
  return a | (b << 16);
}
// lane^32 exchange via shfl (ds_bpermute) — semantics proven good (r4/r5).
// NOTE: __builtin_amdgcn_permlane32_swap(u,u) is NOT usable: r3/r6 failures.
__device__ __forceinline__ float xswap_max(float x) {
  return fmaxf(x, __shfl_xor(x, 32));
}
__device__ __forceinline__ float xswap_sum(float x) {
  return x + __shfl_xor(x, 32);
}

// ---------------- cast kernels ----------------
__global__ __launch_bounds__(256) void cast_x_k(const float* __restrict__ in,
                                                bf16_t* __restrict__ out, int n8) {
  int i = blockIdx.x * 256 + threadIdx.x;
  if (i >= n8) return;
  const float4* p = (const float4*)in + 2 * (size_t)i;
  float4 a = p[0], b = p[1];
  bf16x8 r = { (__bf16)a.x, (__bf16)a.y, (__bf16)a.z, (__bf16)a.w,
               (__bf16)b.x, (__bf16)b.y, (__bf16)b.z, (__bf16)b.w };
  *((bf16x8*)out + i) = r;
}

__global__ __launch_bounds__(256) void cast_w_k(const float* __restrict__ wq,
                                                const float* __restrict__ wk,
                                                const float* __restrict__ wv,
                                                const float* __restrict__ wo,
                                                bf16_t* __restrict__ outbase) {
  const float* src = blockIdx.y == 0 ? wq : blockIdx.y == 1 ? wk : blockIdx.y == 2 ? wv : wo;
  const float sc = (blockIdx.y == 0) ? QSCALE : 1.0f;
  bf16_t* out = outbase + (size_t)blockIdx.y * D_ * D_;
  int i = blockIdx.x * 256 + threadIdx.x;
  const float4* p = (const float4*)src + 2 * (size_t)i;
  float4 a = p[0], b = p[1];
  bf16x8 r = { (__bf16)(a.x*sc), (__bf16)(a.y*sc), (__bf16)(a.z*sc), (__bf16)(a.w*sc),
               (__bf16)(b.x*sc), (__bf16)(b.y*sc), (__bf16)(b.z*sc), (__bf16)(b.w*sc) };
  *((bf16x8*)out + i) = r;
}

// ---------------- 128x128 NT GEMM core (C = A * W^T) ----------------
template<typename OUT>
__device__ __forceinline__ void gemm_bt_128(const bf16_t* __restrict__ A,
                                            const bf16_t* __restrict__ W,
                                            OUT* __restrict__ C,
                                            int Kdim, int ldc_n, int brow, int bcol) {
  __shared__ __align__(16) bf16_t As[128 * 32];
  __shared__ __align__(16) bf16_t Bs[128 * 32];
  const int lane = threadIdx.x & 63;
  const int w    = threadIdx.x >> 6;
  const int lo   = lane & 15, hi = lane >> 4;
  const int wr   = w >> 1, wc = w & 1;

  f32x4 acc[4][4];
  #pragma unroll
  for (int i = 0; i < 4; ++i)
    #pragma unroll
    for (int j = 0; j < 4; ++j) acc[i][j] = (f32x4){0.f, 0.f, 0.f, 0.f};

  for (int kt = 0; kt < Kdim; kt += 32) {
    #pragma unroll
    for (int i = 0; i < 2; ++i) {
      int chunk = w * 2 + i;
      int r = chunk * 16 + (lane >> 2);
      int c = (lane & 3) * 8;
      async16(A + (size_t)(brow + r) * Kdim + kt + c, (char*)As + chunk * 1024);
      async16(W + (size_t)(bcol + r) * Kdim + kt + c, (char*)Bs + chunk * 1024);
    }
    __syncthreads();
    bf16x8 af[4], bfr[4];
    #pragma unroll
    for (int mi = 0; mi < 4; ++mi)
      af[mi] = *(const bf16x8*)&As[(wr * 64 + mi * 16 + lo) * 32 + hi * 8];
    #pragma unroll
    for (int ni = 0; ni < 4; ++ni)
      bfr[ni] = *(const bf16x8*)&Bs[(wc * 64 + ni * 16 + lo) * 32 + hi * 8];
    #pragma unroll
    for (int mi = 0; mi < 4; ++mi)
      #pragma unroll
      for (int ni = 0; ni < 4; ++ni)
        acc[mi][ni] = MFMA16(af[mi], bfr[ni], acc[mi][ni]);
    __syncthreads();
  }

  #pragma unroll
  for (int mi = 0; mi < 4; ++mi)
    #pragma unroll
    for (int ni = 0; ni < 4; ++ni)
      #pragma unroll
      for (int i = 0; i < 4; ++i) {
        int row = brow + wr * 64 + mi * 16 + hi * 4 + i;
        int col = bcol + wc * 64 + ni * 16 + lo;
        C[(size_t)row * ldc_n + col] = (OUT)acc[mi][ni][i];
      }
}

__global__ __launch_bounds__(256) void qkv_gemm_k(const bf16_t* __restrict__ xb,
                                                  const bf16_t* __restrict__ wqb,
                                                  const bf16_t* __restrict__ wkb,
                                                  const bf16_t* __restrict__ wvb,
                                                  bf16_t* __restrict__ Q,
                                                  bf16_t* __restrict__ K,
                                                  bf16_t* __restrict__ V) {
  const bf16_t* W = blockIdx.z == 0 ? wqb : blockIdx.z == 1 ? wkb : wvb;
  bf16_t* C       = blockIdx.z == 0 ? Q   : blockIdx.z == 1 ? K   : V;
  gemm_bt_128<bf16_t>(xb, W, C, D_, D_, blockIdx.y * 128, blockIdx.x * 128);
}

__global__ __launch_bounds__(256) void out_gemm_k(const bf16_t* __restrict__ O,
                                                  const bf16_t* __restrict__ wob,
                                                  float* __restrict__ Y) {
  gemm_bt_128<float>(O, wob, Y, D_, D_, blockIdx.y * 128, blockIdx.x * 128);
}

// ---------------- V transpose: V(B,T,D) -> Vt[(b*H+h)*64+dh][T] ----------------
__global__ __launch_bounds__(256) void vt_k(const bf16_t* __restrict__ V,
                                            bf16_t* __restrict__ Vt) {
  __shared__ bf16_t Tl[64][68];
  const int t0 = blockIdx.x * 64;
  const int bh = blockIdx.y, b = bh >> 4, h = bh & 15;
  const int tid = threadIdx.x;
  #pragma unroll
  for (int it = 0; it < 2; ++it) {
    int idx = it * 256 + tid;
    int r = idx >> 3, c8 = (idx & 7) * 8;
    *(bf16x8*)&Tl[r][c8] = *(const bf16x8*)&V[((size_t)(b * T_ + t0 + r)) * D_ + h * 64 + c8];
  }
  __syncthreads();
  #pragma unroll
  for (int it = 0; it < 2; ++it) {
    int idx = it * 256 + tid;
    int dh = idx >> 3, tc = (idx & 7) * 8;
    bf16x8 v;
    #pragma unroll
    for (int j = 0; j < 8; ++j) v[j] = Tl[tc + j][dh];
    *(bf16x8*)&Vt[((size_t)bh * 64 + dh) * T_ + t0 + tc] = v;
  }
}

// ---------------- flash attention: 4-wave blocks, 4 blocks/CU ----------------
// Block = 256 threads = 4 waves; ONE q-tile (128 rows, 32/wave); one 64-row KV
// tile per iteration, double-buffered (LDS 32KB). NO __launch_bounds__ min-wave
// request: r11 showed (256,5) forces VGPR 48 + scratch spill (WRITE_SIZE 27MB,
// 2.5x slowdown). Natural allocation ~90 VGPR -> 4 independent blocks/CU.
// tau-trick: QK^T A-rows permuted so PV B-fragment = own regs (no shuffles).
// Grid (B*H, 16), qt = 15-y: big blocks dispatch first; flat%8 = bh%8 keeps
// each head's KV on one XCD (L2-resident, r8-verified FETCH 72->12MB).
__global__ __launch_bounds__(256) void attn_k(const bf16_t* __restrict__ Q,
                                              const bf16_t* __restrict__ K,
                                              const bf16_t* __restrict__ Vt,
                                              bf16_t* __restrict__ O) {
  const int bh = blockIdx.x, b = bh >> 4, h = bh & 15;
  const int qt = 15 - (int)blockIdx.y;
  const int tid = threadIdx.x;

  __shared__ __align__(16) char smem[32768];   // [2 buf][K 8KB | V 8KB]

  const bf16_t* Kt0 = K + ((size_t)b * T_) * D_ + h * 64;
  const bf16_t* Vt0 = Vt + (size_t)bh * 64 * T_;

  const int lane = tid & 63, wl = tid >> 6;
  const int ln = lane & 31, hi = lane >> 5;
  // tau: swap quads 1<->2 within each 16 (involution)
  const int tau = (ln & ~12) | (((ln & 4) << 1) | ((ln & 8) >> 1));

  const int q_abs = qt * 128 + wl * 32 + ln;
  bf16x8 qf[4];
  {
    const bf16_t* Qrow = Q + ((size_t)b * T_ + q_abs) * D_ + h * 64;
    #pragma unroll
    for (int ks = 0; ks < 4; ++ks)
      qf[ks] = *(const bf16x8*)(Qrow + ks * 16 + hi * 8);
  }

  f32x16 o0 = zero16(), o1 = zero16();   // O^T: rows=dh (0..31 / 32..63), col=q=ln
  float m = -1e30f, l = 0.f;

  const int jc = 2 * qt + 2;             // KV tiles for this q-tile
  const int jd = 2 * qt + (wl >> 1);     // my wave's diagonal KV tile

#define STAGE4(BUF, TT)                                                       \
  {                                                                           \
    char* kd = smem + (BUF) * 16384;                                          \
    char* vd = smem + (BUF) * 16384 + 8192;                                   \
    _Pragma("unroll")                                                         \
    for (int it = 0; it < 2; ++it) {                                          \
      int c = it * 256 + tid;                                                 \
      int row = c >> 3, sl = c & 7;                                           \
      int slg = sl ^ (row & 7);                                               \
      async16(Kt0 + ((size_t)((TT) * 64 + row)) * D_ + slg * 8, kd + c * 16); \
      async16(Vt0 + (size_t)row * T_ + (TT) * 64 + slg * 8, vd + c * 16);     \
    }                                                                         \
  }

  // P regs are already in fragment order (tau-trick): 4 pk2, no shuffles.
#define PACK_PV4(PS, KS, VB)                                                  \
  {                                                                           \
    const int r0 = ((KS) & 1) * 8;                                            \
    u32x4 pw = {pk2((PS)[r0 + 0], (PS)[r0 + 1]),                              \
                pk2((PS)[r0 + 2], (PS)[r0 + 3]),                              \
                pk2((PS)[r0 + 4], (PS)[r0 + 5]),                              \
                pk2((PS)[r0 + 6], (PS)[r0 + 7])};                             \
    bf16x8 pb = __builtin_bit_cast(bf16x8, pw);                               \
    const int sg = (KS) * 2 + hi;                                             \
    int row = ln;                                                             \
    bf16x8 vf0 = *(const bf16x8*)((VB) + row * 64 + ((sg ^ (row & 7)) * 8));  \
    o0 = MFMA32(vf0, pb, o0);                                                 \
    row = 32 + ln;                                                            \
    bf16x8 vf1 = *(const bf16x8*)((VB) + row * 64 + ((sg ^ (row & 7)) * 8));  \
    o1 = MFMA32(vf1, pb, o1);                                                 \
  }

  STAGE4(0, 0)
  int cur = 0;
  for (int j = 0; j < jc; ++j) {
    if (j + 1 < jc) {
      STAGE4(cur ^ 1, j + 1)
      asm volatile("s_waitcnt vmcnt(4)" ::: "memory");
    } else {
      asm volatile("s_waitcnt vmcnt(0)" ::: "memory");
    }
    __builtin_amdgcn_s_barrier();

    if (j <= jd) {
      const bf16_t* Kb = (const bf16_t*)(smem + cur * 16384);
      const bf16_t* Vb = (const bf16_t*)(smem + cur * 16384 + 8192);
      // S^T = K . Q^T with tau-permuted A rows: reg r holds P at
      // kv = (r&7) + 16*(r>>3) + 8*hi  (+32 for s1)
      f32x16 s0 = zero16(), s1 = zero16();
      __builtin_amdgcn_s_setprio(1);
      #pragma unroll
      for (int ks = 0; ks < 4; ++ks) {
        const int sg = ks * 2 + hi;
        int row = tau;
        bf16x8 kf0 = *(const bf16x8*)(Kb + row * 64 + ((sg ^ (row & 7)) * 8));
        s0 = MFMA32(kf0, qf[ks], s0);
        row = 32 + tau;
        bf16x8 kf1 = *(const bf16x8*)(Kb + row * 64 + ((sg ^ (row & 7)) * 8));
        s1 = MFMA32(kf1, qf[ks], s1);
      }
      __builtin_amdgcn_s_setprio(0);
      if (j == jd) {
        const int kv0 = j * 64;
        #pragma unroll
        for (int r = 0; r < 16; ++r) {
          const int pos = (r & 7) + 16 * (r >> 3) + 8 * hi;
          if (kv0 + pos      > q_abs) s0[r] = -3e38f;
          if (kv0 + 32 + pos > q_abs) s1[r] = -3e38f;
        }
      }
      // online softmax (log2 domain), tree reductions, defer-max
      float t[16];
      #pragma unroll
      for (int r = 0; r < 16; ++r) t[r] = fmaxf(s0[r], s1[r]);
      #pragma unroll
      for (int st = 8; st >= 1; st >>= 1)
        #pragma unroll
        for (int i = 0; i < st; ++i) t[i] = fmaxf(t[i], t[i + st]);
      float pmax = xswap_max(t[0]);
      if (!__all(pmax - m <= DEFER_THR)) {
        float mn   = fmaxf(m, pmax);
        float corr = EXP2(m - mn);
        m = mn;
        l *= corr;
        #pragma unroll
        for (int r = 0; r < 16; ++r) { o0[r] *= corr; o1[r] *= corr; }
      }
      float u[16];
      #pragma unroll
      for (int r = 0; r < 16; ++r) {
        float p0 = EXP2(s0[r] - m); s0[r] = p0;
        float p1 = EXP2(s1[r] - m); s1[r] = p1;
        u[r] = p0 + p1;
      }
      #pragma unroll
      for (int st = 8; st >= 1; st >>= 1)
        #pragma unroll
        for (int i = 0; i < st; ++i) u[i] += u[i + st];
      l += xswap_sum(u[0]);
      __builtin_amdgcn_s_setprio(1);
      PACK_PV4(s0, 0, Vb)
      PACK_PV4(s0, 1, Vb)
      PACK_PV4(s1, 2, Vb)
      PACK_PV4(s1, 3, Vb)
      __builtin_amdgcn_s_setprio(0);
    }
    __builtin_amdgcn_s_barrier();
    cur ^= 1;
  }

  // epilogue: lane owns q row q_abs; o0/o1 rows are dh
  {
    float rl = 1.0f / l;
    bf16_t* Orow = O + ((size_t)b * T_ + q_abs) * D_ + h * 64;
    #pragma unroll
    for (int g = 0; g < 4; ++g) {
      const int dh0 = 8 * g + 4 * hi;
      bf16x4 v0, v1;
      #pragma unroll
      for (int jj = 0; jj < 4; ++jj) {
        v0[jj] = (__bf16)(o0[4 * g + jj] * rl);
        v1[jj] = (__bf16)(o1[4 * g + jj] * rl);
      }
      *(bf16x4*)(Orow + dh0)      = v0;
      *(bf16x4*)(Orow + 32 + dh0) = v1;
    }
  }
#undef STAGE4
#undef PACK_PV4
}

// ---------------- launcher ----------------
extern "C" void kernel_launch(void* const* d_in, const int* in_sizes, int n_in,
                              void* d_out, int out_size, void* d_ws, size_t ws_size,
                              hipStream_t stream) {
  const float* x  = (const float*)d_in[0];
  const float* wq = (const float*)d_in[1];
  const float* wk = (const float*)d_in[2];
  const float* wv = (const float*)d_in[3];
  const float* wo = (const float*)d_in[4];
  float* out = (float*)d_out;

  char* ws = (char*)d_ws;
  bf16_t* xb  = (bf16_t*)(ws);                       // 8 MB
  bf16_t* wqb = (bf16_t*)(ws + (size_t)( 8 << 20));  // 2 MB each
  bf16_t* wkb = (bf16_t*)(ws + (size_t)(10 << 20));
  bf16_t* wvb = (bf16_t*)(ws + (size_t)(12 << 20));
  bf16_t* wob = (bf16_t*)(ws + (size_t)(14 << 20));
  bf16_t* Qb  = (bf16_t*)(ws + (size_t)(16 << 20));  // 8 MB
  bf16_t* Kb  = (bf16_t*)(ws + (size_t)(24 << 20));  // 8 MB
  bf16_t* Vb  = (bf16_t*)(ws + (size_t)(32 << 20));  // 8 MB
  bf16_t* Vtb = (bf16_t*)(ws + (size_t)(40 << 20));  // 8 MB
  bf16_t* Ob  = Vb;   // Vb dead after vt_k; attn output reuses its slot

  (void)in_sizes; (void)n_in; (void)out_size; (void)ws_size;

  cast_x_k<<<dim3(M_ * D_ / 8 / 256), 256, 0, stream>>>(x, xb, M_ * D_ / 8);
  cast_w_k<<<dim3(D_ * D_ / 8 / 256, 4), 256, 0, stream>>>(wq, wk, wv, wo, wqb);
  qkv_gemm_k<<<dim3(D_ / 128, M_ / 128, 3), 256, 0, stream>>>(xb, wqb, wkb, wvb, Qb, Kb, Vb);
  vt_k<<<dim3(T_ / 64, B_ * H_), 256, 0, stream>>>(Vb, Vtb);
  attn_k<<<dim3(B_ * H_, T_ / 128), 256, 0, stream>>>(Qb, Kb, Vtb, Ob);
  out_gemm_k<<<dim3(D_ / 128, M_ / 128), 256, 0, stream>>>(Ob, wob, out);
}

// Round 13
// 116.796 us; speedup vs baseline: 1.4778x; 1.0799x over previous
//
#include <hip/hip_runtime.h>
#include <hip/hip_bf16.h>
#include <cstdint>
#include <cstddef>

#define B_  2
#define T_  2048
#define D_  1024
#define H_  16
#define M_  (B_*T_)   // 4096 rows total

typedef __bf16 bf16_t;
typedef __attribute__((ext_vector_type(8))) __bf16 bf16x8;
typedef __attribute__((ext_vector_type(4))) __bf16 bf16x4;
typedef __attribute__((ext_vector_type(4))) float f32x4;
typedef __attribute__((ext_vector_type(16))) float f32x16;
typedef unsigned int u32;
typedef __attribute__((ext_vector_type(4))) u32 u32x4;

#define MFMA16(a,b,c) __builtin_amdgcn_mfma_f32_16x16x32_bf16(a,b,c,0,0,0)
#define MFMA32(a,b,c) __builtin_amdgcn_mfma_f32_32x32x16_bf16(a,b,c,0,0,0)
#define EXP2(x) __builtin_amdgcn_exp2f(x)

// 0.125 * log2(e): folds 1/sqrt(DH) and the e->2 base change into Wq
#define QSCALE 0.18033688011112042f
// defer-max threshold in log2 domain: skip O-rescale while P <= 2^10
#define DEFER_THR 10.0f

__device__ inline void async16(const void* g, void* l) {
  __builtin_amdgcn_global_load_lds((const __attribute__((address_space(1))) void*)g,
                                   (__attribute__((address_space(3))) void*)l, 16, 0, 0);
}

__device__ __forceinline__ f32x16 zero16() {
  f32x16 z;
  #pragma unroll
  for (int i = 0; i < 16; ++i) z[i] = 0.f;
  return z;
}

// pack two f32 -> one u32 of 2 bf16 (compiler fuses to v_cvt_pk_bf16_f32)
__device__ __forceinline__ u32 pk2(float lo, float hi) {
  u32 a = __builtin_bit_cast(unsigned short, (__bf16)lo);
  u32 b = __builtin_bit_cast(unsigned short, (__bf16)hi);
  return a | (b << 16);
}
// lane^32 exchange via shfl (ds_bpermute) — semantics proven good (r4/r5).
// NOTE: __builtin_amdgcn_permlane32_swap(u,u) is NOT usable: r3/r6 failures.
__device__ __forceinline__ float xswap_max(float x) {
  return fmaxf(x, __shfl_xor(x, 32));
}
__device__ __forceinline__ float xswap_sum(float x) {
  return x + __shfl_xor(x, 32);
}

// ---------------- cast kernels ----------------
__global__ __launch_bounds__(256) void cast_x_k(const float* __restrict__ in,
                                                bf16_t* __restrict__ out, int n8) {
  int i = blockIdx.x * 256 + threadIdx.x;
  if (i >= n8) return;
  const float4* p = (const float4*)in + 2 * (size_t)i;
  float4 a = p[0], b = p[1];
  bf16x8 r = { (__bf16)a.x, (__bf16)a.y, (__bf16)a.z, (__bf16)a.w,
               (__bf16)b.x, (__bf16)b.y, (__bf16)b.z, (__bf16)b.w };
  *((bf16x8*)out + i) = r;
}

__global__ __launch_bounds__(256) void cast_w_k(const float* __restrict__ wq,
                                                const float* __restrict__ wk,
                                                const float* __restrict__ wv,
                                                const float* __restrict__ wo,
                                                bf16_t* __restrict__ outbase) {
  const float* src = blockIdx.y == 0 ? wq : blockIdx.y == 1 ? wk : blockIdx.y == 2 ? wv : wo;
  const float sc = (blockIdx.y == 0) ? QSCALE : 1.0f;
  bf16_t* out = outbase + (size_t)blockIdx.y * D_ * D_;
  int i = blockIdx.x * 256 + threadIdx.x;
  const float4* p = (const float4*)src + 2 * (size_t)i;
  float4 a = p[0], b = p[1];
  bf16x8 r = { (__bf16)(a.x*sc), (__bf16)(a.y*sc), (__bf16)(a.z*sc), (__bf16)(a.w*sc),
               (__bf16)(b.x*sc), (__bf16)(b.y*sc), (__bf16)(b.z*sc), (__bf16)(b.w*sc) };
  *((bf16x8*)out + i) = r;
}

// ---------------- 128x128 NT GEMM, double-buffered pipeline (T3-minimum) ----------------
// C = A * W^T. A:(M,K) bf16, W:(N,K) bf16, C:(M,N). Per K-step: issue next
// tile's global_load_lds BEFORE waiting (counted vmcnt(4)) -> stage latency
// hides under current tile's 16 MFMA. Same proven pattern as attn STAGE.
template<typename OUT>
__device__ __forceinline__ void gemm_bt_128db(const bf16_t* __restrict__ A,
                                              const bf16_t* __restrict__ W,
                                              OUT* __restrict__ C,
                                              int Kdim, int ldc_n, int brow, int bcol) {
  __shared__ __align__(16) bf16_t As[2][128 * 32];
  __shared__ __align__(16) bf16_t Bs[2][128 * 32];
  const int lane = threadIdx.x & 63;
  const int w    = threadIdx.x >> 6;
  const int lo   = lane & 15, hi = lane >> 4;
  const int wr   = w >> 1, wc = w & 1;

  f32x4 acc[4][4];
  #pragma unroll
  for (int i = 0; i < 4; ++i)
    #pragma unroll
    for (int j = 0; j < 4; ++j) acc[i][j] = (f32x4){0.f, 0.f, 0.f, 0.f};

#define GSTAGE(BUF, KT)                                                        \
  {                                                                            \
    _Pragma("unroll")                                                          \
    for (int i = 0; i < 2; ++i) {                                              \
      int chunk = w * 2 + i;                                                   \
      int r = chunk * 16 + (lane >> 2);                                        \
      int c = (lane & 3) * 8;                                                  \
      async16(A + (size_t)(brow + r) * Kdim + (KT) + c,                        \
              (char*)As[BUF] + chunk * 1024);                                  \
      async16(W + (size_t)(bcol + r) * Kdim + (KT) + c,                        \
              (char*)Bs[BUF] + chunk * 1024);                                  \
    }                                                                          \
  }

  const int nK = Kdim >> 5;
  GSTAGE(0, 0)
  int cur = 0;
  for (int ki = 0; ki < nK; ++ki) {
    if (ki + 1 < nK) {
      GSTAGE(cur ^ 1, (ki + 1) * 32)
      asm volatile("s_waitcnt vmcnt(4)" ::: "memory");
    } else {
      asm volatile("s_waitcnt vmcnt(0)" ::: "memory");
    }
    __builtin_amdgcn_s_barrier();
    bf16x8 af[4], bfr[4];
    #pragma unroll
    for (int mi = 0; mi < 4; ++mi)
      af[mi] = *(const bf16x8*)&As[cur][(wr * 64 + mi * 16 + lo) * 32 + hi * 8];
    #pragma unroll
    for (int ni = 0; ni < 4; ++ni)
      bfr[ni] = *(const bf16x8*)&Bs[cur][(wc * 64 + ni * 16 + lo) * 32 + hi * 8];
    __builtin_amdgcn_s_setprio(1);
    #pragma unroll
    for (int mi = 0; mi < 4; ++mi)
      #pragma unroll
      for (int ni = 0; ni < 4; ++ni)
        acc[mi][ni] = MFMA16(af[mi], bfr[ni], acc[mi][ni]);
    __builtin_amdgcn_s_setprio(0);
    __builtin_amdgcn_s_barrier();
    cur ^= 1;
  }
#undef GSTAGE

  #pragma unroll
  for (int mi = 0; mi < 4; ++mi)
    #pragma unroll
    for (int ni = 0; ni < 4; ++ni)
      #pragma unroll
      for (int i = 0; i < 4; ++i) {
        int row = brow + wr * 64 + mi * 16 + hi * 4 + i;
        int col = bcol + wc * 64 + ni * 16 + lo;
        C[(size_t)row * ldc_n + col] = (OUT)acc[mi][ni][i];
      }
}

__global__ __launch_bounds__(256) void qkv_gemm_k(const bf16_t* __restrict__ xb,
                                                  const bf16_t* __restrict__ wqb,
                                                  const bf16_t* __restrict__ wkb,
                                                  const bf16_t* __restrict__ wvb,
                                                  bf16_t* __restrict__ Q,
                                                  bf16_t* __restrict__ K,
                                                  bf16_t* __restrict__ V) {
  const bf16_t* W = blockIdx.z == 0 ? wqb : blockIdx.z == 1 ? wkb : wvb;
  bf16_t* C       = blockIdx.z == 0 ? Q   : blockIdx.z == 1 ? K   : V;
  gemm_bt_128db<bf16_t>(xb, W, C, D_, D_, blockIdx.y * 128, blockIdx.x * 128);
}

__global__ __launch_bounds__(256) void out_gemm_k(const bf16_t* __restrict__ O,
                                                  const bf16_t* __restrict__ wob,
                                                  float* __restrict__ Y) {
  gemm_bt_128db<float>(O, wob, Y, D_, D_, blockIdx.y * 128, blockIdx.x * 128);
}

// ---------------- V transpose: V(B,T,D) -> Vt[(b*H+h)*64+dh][T] ----------------
__global__ __launch_bounds__(256) void vt_k(const bf16_t* __restrict__ V,
                                            bf16_t* __restrict__ Vt) {
  __shared__ bf16_t Tl[64][68];
  const int t0 = blockIdx.x * 64;
  const int bh = blockIdx.y, b = bh >> 4, h = bh & 15;
  const int tid = threadIdx.x;
  #pragma unroll
  for (int it = 0; it < 2; ++it) {
    int idx = it * 256 + tid;
    int r = idx >> 3, c8 = (idx & 7) * 8;
    *(bf16x8*)&Tl[r][c8] = *(const bf16x8*)&V[((size_t)(b * T_ + t0 + r)) * D_ + h * 64 + c8];
  }
  __syncthreads();
  #pragma unroll
  for (int it = 0; it < 2; ++it) {
    int idx = it * 256 + tid;
    int dh = idx >> 3, tc = (idx & 7) * 8;
    bf16x8 v;
    #pragma unroll
    for (int j = 0; j < 8; ++j) v[j] = Tl[tc + j][dh];
    *(bf16x8*)&Vt[((size_t)bh * 64 + dh) * T_ + t0 + tc] = v;
  }
}

// ---------------- flash attention: r10 structure (measured 41.8us) ----------------
// Block = 512 threads. Waves 0-3 (group A): KV tiles [0, qt]; waves 4-7 (B):
// [qt+1, 2qt+1]. Partials merged through LDS. tau-trick PV (no shuffles).
// qt map pairs near-equal durations on a CU (r9/r10 lesson: co-resident
// blocks hide each other's latency; maximize the min of each pair).
// Grid (B*H, 16): id%8 = bh%8 keeps each head on one XCD (L2-resident KV).
__global__ __launch_bounds__(512) void attn_k(const bf16_t* __restrict__ Q,
                                              const bf16_t* __restrict__ K,
                                              const bf16_t* __restrict__ Vt,
                                              bf16_t* __restrict__ O) {
  const int bh = blockIdx.x, b = bh >> 4, h = bh & 15;
  const int yy = (int)blockIdx.y;
  const int qt = (yy < 8) ? (15 - 2 * yy) : (30 - 2 * yy);
  const int tid = threadIdx.x;

  __shared__ __align__(16) char smem[65536];

  const bf16_t* Kt0 = K + ((size_t)b * T_) * D_ + h * 64;
  const bf16_t* Vt0 = Vt + (size_t)bh * 64 * T_;

  const int lane = tid & 63, w = tid >> 6;
  const int wl = w & 3, wg = w >> 2;
  const int ln = lane & 31, hi = lane >> 5;
  const int tl = tid & 255;
  // tau: swap quads 1<->2 within each 16 (involution)
  const int tau = (ln & ~12) | (((ln & 4) << 1) | ((ln & 8) >> 1));
  char* sgbase = smem + ((tid >= 256) ? 32768 : 0);  // staging base (thread's group)
  char* cgbase = smem + wg * 32768;                  // compute base (wave's group)
  float* mo = (float*)smem;                          // merge: [4][64][33] f32
  float* ml = (float*)(smem + 33792);                // merge: [4][64][2]  f32

  const int q_abs = qt * 128 + wl * 32 + ln;
  bf16x8 qf[4];
  {
    const bf16_t* Qrow = Q + ((size_t)b * T_ + q_abs) * D_ + h * 64;
    #pragma unroll
    for (int ks = 0; ks < 4; ++ks)
      qf[ks] = *(const bf16x8*)(Qrow + ks * 16 + hi * 8);
  }

  f32x16 o0 = zero16(), o1 = zero16();   // O^T: rows=dh (0..31 / 32..63), col=q=ln
  float m = -1e30f, l = 0.f;

  const int jc    = qt + 1;              // iterations per group
  const int jd    = 2 * qt + (wl >> 1);  // my diagonal KV tile
  const int tbase = wg ? (qt + 1) : 0;   // group KV range start

#define STAGE8(BUF, TT)                                                       \
  {                                                                           \
    char* kd = sgbase + (BUF) * 8192;                                         \
    char* vd = sgbase + 16384 + (BUF) * 8192;                                 \
    _Pragma("unroll")                                                         \
    for (int it = 0; it < 2; ++it) {                                          \
      int c = it * 256 + tl;                                                  \
      int row = c >> 3, sl = c & 7;                                           \
      int slg = sl ^ (row & 7);                                               \
      async16(Kt0 + ((size_t)((TT) * 64 + row)) * D_ + slg * 8, kd + c * 16); \
      async16(Vt0 + (size_t)row * T_ + (TT) * 64 + slg * 8, vd + c * 16);     \
    }                                                                         \
  }

  // P regs are already in fragment order (tau-trick): 4 pk2, no shuffles.
#define PACK_PV8(PS, KS, VB)                                                  \
  {                                                                           \
    const int r0 = ((KS) & 1) * 8;                                            \
    u32x4 pw = {pk2((PS)[r0 + 0], (PS)[r0 + 1]),                              \
                pk2((PS)[r0 + 2], (PS)[r0 + 3]),                              \
                pk2((PS)[r0 + 4], (PS)[r0 + 5]),                              \
                pk2((PS)[r0 + 6], (PS)[r0 + 7])};                             \
    bf16x8 pb = __builtin_bit_cast(bf16x8, pw);                               \
    const int sg = (KS) * 2 + hi;                                             \
    int row = ln;                                                             \
    bf16x8 vf0 = *(const bf16x8*)((VB) + row * 64 + ((sg ^ (row & 7)) * 8));  \
    o0 = MFMA32(vf0, pb, o0);                                                 \
    row = 32 + ln;                                                            \
    bf16x8 vf1 = *(const bf16x8*)((VB) + row * 64 + ((sg ^ (row & 7)) * 8));  \
    o1 = MFMA32(vf1, pb, o1);                                                 \
  }

  STAGE8(0, tbase)
  int cur = 0;
  for (int j = 0; j < jc; ++j) {
    if (j + 1 < jc) {
      STAGE8(cur ^ 1, tbase + j + 1)
      asm volatile("s_waitcnt vmcnt(4)" ::: "memory");
    } else {
      asm volatile("s_waitcnt vmcnt(0)" ::: "memory");
    }
    __builtin_amdgcn_s_barrier();

    const int tt = tbase + j;
    if (tt <= jd) {
      const bf16_t* Kb = (const bf16_t*)(cgbase + cur * 8192);
      const bf16_t* Vb = (const bf16_t*)(cgbase + 16384 + cur * 8192);
      // S^T = K . Q^T with tau-permuted A rows: reg r holds P at
      // kv = (r&7) + 16*(r>>3) + 8*hi  (+32 for s1)
      f32x16 s0 = zero16(), s1 = zero16();
      __builtin_amdgcn_s_setprio(1);
      #pragma unroll
      for (int ks = 0; ks < 4; ++ks) {
        const int sg = ks * 2 + hi;
        int row = tau;
        bf16x8 kf0 = *(const bf16x8*)(Kb + row * 64 + ((sg ^ (row & 7)) * 8));
        s0 = MFMA32(kf0, qf[ks], s0);
        row = 32 + tau;
        bf16x8 kf1 = *(const bf16x8*)(Kb + row * 64 + ((sg ^ (row & 7)) * 8));
        s1 = MFMA32(kf1, qf[ks], s1);
      }
      __builtin_amdgcn_s_setprio(0);
      if (tt == jd) {
        const int kv0 = tt * 64;
        #pragma unroll
        for (int r = 0; r < 16; ++r) {
          const int pos = (r & 7) + 16 * (r >> 3) + 8 * hi;
          if (kv0 + pos      > q_abs) s0[r] = -3e38f;
          if (kv0 + 32 + pos > q_abs) s1[r] = -3e38f;
        }
      }
      // online softmax (log2 domain), tree reductions, defer-max
      float t[16];
      #pragma unroll
      for (int r = 0; r < 16; ++r) t[r] = fmaxf(s0[r], s1[r]);
      #pragma unroll
      for (int st = 8; st >= 1; st >>= 1)
        #pragma unroll
        for (int i = 0; i < st; ++i) t[i] = fmaxf(t[i], t[i + st]);
      float pmax = xswap_max(t[0]);
      if (!__all(pmax - m <= DEFER_THR)) {
        float mn   = fmaxf(m, pmax);
        float corr = EXP2(m - mn);
        m = mn;
        l *= corr;
        #pragma unroll
        for (int r = 0; r < 16; ++r) { o0[r] *= corr; o1[r] *= corr; }
      }
      float u[16];
      #pragma unroll
      for (int r = 0; r < 16; ++r) {
        float p0 = EXP2(s0[r] - m); s0[r] = p0;
        float p1 = EXP2(s1[r] - m); s1[r] = p1;
        u[r] = p0 + p1;
      }
      #pragma unroll
      for (int st = 8; st >= 1; st >>= 1)
        #pragma unroll
        for (int i = 0; i < st; ++i) u[i] += u[i + st];
      l += xswap_sum(u[0]);
      __builtin_amdgcn_s_setprio(1);
      PACK_PV8(s0, 0, Vb)
      PACK_PV8(s0, 1, Vb)
      PACK_PV8(s1, 2, Vb)
      PACK_PV8(s1, 3, Vb)
      __builtin_amdgcn_s_setprio(0);
    }
    __builtin_amdgcn_s_barrier();
    cur ^= 1;
  }

  // ---- merge group B partials into group A, then store ----
  if (wg == 1) {
    float* mop = mo + ((size_t)wl * 64 + lane) * 33;
    #pragma unroll
    for (int r = 0; r < 16; ++r) { mop[r] = o0[r]; mop[16 + r] = o1[r]; }
    float* mlp = ml + ((size_t)wl * 64 + lane) * 2;
    mlp[0] = m; mlp[1] = l;
  }
  __syncthreads();
  if (wg == 0) {
    const float* mop = mo + ((size_t)wl * 64 + lane) * 33;
    const float* mlp = ml + ((size_t)wl * 64 + lane) * 2;
    float mB = mlp[0], lB = mlp[1];
    float mS = fmaxf(m, mB);
    float cA = EXP2(m - mS), cB = EXP2(mB - mS);
    float lS = l * cA + lB * cB;
    float rl = 1.0f / lS;
    bf16_t* Orow = O + ((size_t)b * T_ + q_abs) * D_ + h * 64;
    #pragma unroll
    for (int g = 0; g < 4; ++g) {
      const int dh0 = 8 * g + 4 * hi;
      bf16x4 v0, v1;
      #pragma unroll
      for (int jj = 0; jj < 4; ++jj) {
        v0[jj] = (__bf16)((o0[4 * g + jj] * cA + mop[4 * g + jj] * cB) * rl);
        v1[jj] = (__bf16)((o1[4 * g + jj] * cA + mop[16 + 4 * g + jj] * cB) * rl);
      }
      *(bf16x4*)(Orow + dh0)      = v0;
      *(bf16x4*)(Orow + 32 + dh0) = v1;
    }
  }
#undef STAGE8
#undef PACK_PV8
}

// ---------------- launcher ----------------
extern "C" void kernel_launch(void* const* d_in, const int* in_sizes, int n_in,
                              void* d_out, int out_size, void* d_ws, size_t ws_size,
                              hipStream_t stream) {
  const float* x  = (const float*)d_in[0];
  const float* wq = (const float*)d_in[1];
  const float* wk = (const float*)d_in[2];
  const float* wv = (const float*)d_in[3];
  const float* wo = (const float*)d_in[4];
  float* out = (float*)d_out;

  char* ws = (char*)d_ws;
  bf16_t* xb  = (bf16_t*)(ws);                       // 8 MB
  bf16_t* wqb = (bf16_t*)(ws + (size_t)( 8 << 20));  // 2 MB each
  bf16_t* wkb = (bf16_t*)(ws + (size_t)(10 << 20));
  bf16_t* wvb = (bf16_t*)(ws + (size_t)(12 << 20));
  bf16_t* wob = (bf16_t*)(ws + (size_t)(14 << 20));
  bf16_t* Qb  = (bf16_t*)(ws + (size_t)(16 << 20));  // 8 MB
  bf16_t* Kb  = (bf16_t*)(ws + (size_t)(24 << 20));  // 8 MB
  bf16_t* Vb  = (bf16_t*)(ws + (size_t)(32 << 20));  // 8 MB
  bf16_t* Vtb = (bf16_t*)(ws + (size_t)(40 << 20));  // 8 MB
  bf16_t* Ob  = Vb;   // Vb dead after vt_k; attn output reuses its slot

  (void)in_sizes; (void)n_in; (void)out_size; (void)ws_size;

  cast_x_k<<<dim3(M_ * D_ / 8 / 256), 256, 0, stream>>>(x, xb, M_ * D_ / 8);
  cast_w_k<<<dim3(D_ * D_ / 8 / 256, 4), 256, 0, stream>>>(wq, wk, wv, wo, wqb);
  qkv_gemm_k<<<dim3(D_ / 128, M_ / 128, 3), 256, 0, stream>>>(xb, wqb, wkb, wvb, Qb, Kb, Vb);
  vt_k<<<dim3(T_ / 64, B_ * H_), 256, 0, stream>>>(Vb, Vtb);
  attn_k<<<dim3(B_ * H_, T_ / 128), 512, 0, stream>>>(Qb, Kb, Vtb, Ob);
  out_gemm_k<<<dim3(D_ / 128, M_ / 128), 256, 0, stream>>>(Ob, wob, out);
}

// Round 14
// 116.537 us; speedup vs baseline: 1.4810x; 1.0022x over previous
//
#include <hip/hip_runtime.h>
#include <hip/hip_bf16.h>
#include <cstdint>
#include <cstddef>

#define B_  2
#define T_  2048
#define D_  1024
#define H_  16
#define M_  (B_*T_)   // 4096 rows total

typedef __bf16 bf16_t;
typedef __attribute__((ext_vector_type(8))) __bf16 bf16x8;
typedef __attribute__((ext_vector_type(4))) __bf16 bf16x4;
typedef __attribute__((ext_vector_type(4))) float f32x4;
typedef __attribute__((ext_vector_type(16))) float f32x16;
typedef unsigned int u32;
typedef __attribute__((ext_vector_type(4))) u32 u32x4;

#define MFMA16(a,b,c) __builtin_amdgcn_mfma_f32_16x16x32_bf16(a,b,c,0,0,0)
#define MFMA32(a,b,c) __builtin_amdgcn_mfma_f32_32x32x16_bf16(a,b,c,0,0,0)
#define EXP2(x) __builtin_amdgcn_exp2f(x)

// 0.125 * log2(e): folds 1/sqrt(DH) and the e->2 base change into Wq
#define QSCALE 0.18033688011112042f
// defer-max threshold in log2 domain: skip O-rescale while P <= 2^10
#define DEFER_THR 10.0f

__device__ inline void async16(const void* g, void* l) {
  __builtin_amdgcn_global_load_lds((const __attribute__((address_space(1))) void*)g,
                                   (__attribute__((address_space(3))) void*)l, 16, 0, 0);
}

__device__ __forceinline__ f32x16 zero16() {
  f32x16 z;
  #pragma unroll
  for (int i = 0; i < 16; ++i) z[i] = 0.f;
  return z;
}

// pack two f32 -> one u32 of 2 bf16 (compiler fuses to v_cvt_pk_bf16_f32)
__device__ __forceinline__ u32 pk2(float lo, float hi) {
  u32 a = __builtin_bit_cast(unsigned short, (__bf16)lo);
  u32 b = __builtin_bit_cast(unsigned short, (__bf16)hi);
  return a | (b << 16);
}
// lane^32 exchange via shfl (ds_bpermute) — semantics proven good (r4/r5).
// NOTE: __builtin_amdgcn_permlane32_swap(u,u) is NOT usable: r3/r6 failures.
__device__ __forceinline__ float xswap_max(float x) {
  return fmaxf(x, __shfl_xor(x, 32));
}
__device__ __forceinline__ float xswap_sum(float x) {
  return x + __shfl_xor(x, 32);
}

// ---------------- fused cast kernel ----------------
// blocks [0,2048): x (4096x1024 f32 -> bf16)
// blocks [2048,4096): wq/wk/wv/wo, 512 blocks each; wq scaled by QSCALE.
__global__ __launch_bounds__(256) void cast_all_k(const float* __restrict__ x,
                                                  const float* __restrict__ wq,
                                                  const float* __restrict__ wk,
                                                  const float* __restrict__ wv,
                                                  const float* __restrict__ wo,
                                                  bf16_t* __restrict__ xb,
                                                  bf16_t* __restrict__ wbase) {
  int bid = blockIdx.x;
  const float* src;
  bf16_t* dst;
  float sc = 1.0f;
  int i;
  if (bid < 2048) {
    src = x; dst = xb; i = bid * 256 + threadIdx.x;
  } else {
    int wsel = (bid - 2048) >> 9;           // /512
    int wblk = (bid - 2048) & 511;
    src = wsel == 0 ? wq : wsel == 1 ? wk : wsel == 2 ? wv : wo;
    if (wsel == 0) sc = QSCALE;
    dst = wbase + (size_t)wsel * D_ * D_;
    i = wblk * 256 + threadIdx.x;
  }
  const float4* p = (const float4*)src + 2 * (size_t)i;
  float4 a = p[0], b = p[1];
  bf16x8 r = { (__bf16)(a.x*sc), (__bf16)(a.y*sc), (__bf16)(a.z*sc), (__bf16)(a.w*sc),
               (__bf16)(b.x*sc), (__bf16)(b.y*sc), (__bf16)(b.z*sc), (__bf16)(b.w*sc) };
  *((bf16x8*)dst + i) = r;
}

// ---------------- 128x128 NT GEMM, double-buffered pipeline ----------------
// C = A * W^T. Issue next tile's global_load_lds BEFORE waiting (counted
// vmcnt(4)); stage latency hides under current tile's 16 MFMA. NO setprio
// (m190/T5: hurts lockstep GEMM). Caller maps blockIdx.x = M-tile so the 8
// blocks sharing an A-panel are co-XCD (flat%8 = m%8) -> A stays in that
// XCD's L2 (r8 mechanism).
template<typename OUT>
__device__ __forceinline__ void gemm_bt_128db(const bf16_t* __restrict__ A,
                                              const bf16_t* __restrict__ W,
                                              OUT* __restrict__ C,
                                              int Kdim, int ldc_n, int brow, int bcol) {
  __shared__ __align__(16) bf16_t As[2][128 * 32];
  __shared__ __align__(16) bf16_t Bs[2][128 * 32];
  const int lane = threadIdx.x & 63;
  const int w    = threadIdx.x >> 6;
  const int lo   = lane & 15, hi = lane >> 4;
  const int wr   = w >> 1, wc = w & 1;

  f32x4 acc[4][4];
  #pragma unroll
  for (int i = 0; i < 4; ++i)
    #pragma unroll
    for (int j = 0; j < 4; ++j) acc[i][j] = (f32x4){0.f, 0.f, 0.f, 0.f};

#define GSTAGE(BUF, KT)                                                        \
  {                                                                            \
    _Pragma("unroll")                                                          \
    for (int i = 0; i < 2; ++i) {                                              \
      int chunk = w * 2 + i;                                                   \
      int r = chunk * 16 + (lane >> 2);                                        \
      int c = (lane & 3) * 8;                                                  \
      async16(A + (size_t)(brow + r) * Kdim + (KT) + c,                        \
              (char*)As[BUF] + chunk * 1024);                                  \
      async16(W + (size_t)(bcol + r) * Kdim + (KT) + c,                        \
              (char*)Bs[BUF] + chunk * 1024);                                  \
    }                                                                          \
  }

  const int nK = Kdim >> 5;
  GSTAGE(0, 0)
  int cur = 0;
  for (int ki = 0; ki < nK; ++ki) {
    if (ki + 1 < nK) {
      GSTAGE(cur ^ 1, (ki + 1) * 32)
      asm volatile("s_waitcnt vmcnt(4)" ::: "memory");
    } else {
      asm volatile("s_waitcnt vmcnt(0)" ::: "memory");
    }
    __builtin_amdgcn_s_barrier();
    bf16x8 af[4], bfr[4];
    #pragma unroll
    for (int mi = 0; mi < 4; ++mi)
      af[mi] = *(const bf16x8*)&As[cur][(wr * 64 + mi * 16 + lo) * 32 + hi * 8];
    #pragma unroll
    for (int ni = 0; ni < 4; ++ni)
      bfr[ni] = *(const bf16x8*)&Bs[cur][(wc * 64 + ni * 16 + lo) * 32 + hi * 8];
    #pragma unroll
    for (int mi = 0; mi < 4; ++mi)
      #pragma unroll
      for (int ni = 0; ni < 4; ++ni)
        acc[mi][ni] = MFMA16(af[mi], bfr[ni], acc[mi][ni]);
    __builtin_amdgcn_s_barrier();
    cur ^= 1;
  }
#undef GSTAGE

  #pragma unroll
  for (int mi = 0; mi < 4; ++mi)
    #pragma unroll
    for (int ni = 0; ni < 4; ++ni)
      #pragma unroll
      for (int i = 0; i < 4; ++i) {
        int row = brow + wr * 64 + mi * 16 + hi * 4 + i;
        int col = bcol + wc * 64 + ni * 16 + lo;
        C[(size_t)row * ldc_n + col] = (OUT)acc[mi][ni][i];
      }
}

// grid (M/128, N/128, 3): blockIdx.x = M-tile (A-panel co-XCD)
__global__ __launch_bounds__(256) void qkv_gemm_k(const bf16_t* __restrict__ xb,
                                                  const bf16_t* __restrict__ wqb,
                                                  const bf16_t* __restrict__ wkb,
                                                  const bf16_t* __restrict__ wvb,
                                                  bf16_t* __restrict__ Q,
                                                  bf16_t* __restrict__ K,
                                                  bf16_t* __restrict__ V) {
  const bf16_t* W = blockIdx.z == 0 ? wqb : blockIdx.z == 1 ? wkb : wvb;
  bf16_t* C       = blockIdx.z == 0 ? Q   : blockIdx.z == 1 ? K   : V;
  gemm_bt_128db<bf16_t>(xb, W, C, D_, D_, blockIdx.x * 128, blockIdx.y * 128);
}

__global__ __launch_bounds__(256) void out_gemm_k(const bf16_t* __restrict__ O,
                                                  const bf16_t* __restrict__ wob,
                                                  float* __restrict__ Y) {
  gemm_bt_128db<float>(O, wob, Y, D_, D_, blockIdx.x * 128, blockIdx.y * 128);
}

// ---------------- V transpose: V(B,T,D) -> Vt[(b*H+h)*64+dh][T] ----------------
__global__ __launch_bounds__(256) void vt_k(const bf16_t* __restrict__ V,
                                            bf16_t* __restrict__ Vt) {
  __shared__ bf16_t Tl[64][68];
  const int t0 = blockIdx.x * 64;
  const int bh = blockIdx.y, b = bh >> 4, h = bh & 15;
  const int tid = threadIdx.x;
  #pragma unroll
  for (int it = 0; it < 2; ++it) {
    int idx = it * 256 + tid;
    int r = idx >> 3, c8 = (idx & 7) * 8;
    *(bf16x8*)&Tl[r][c8] = *(const bf16x8*)&V[((size_t)(b * T_ + t0 + r)) * D_ + h * 64 + c8];
  }
  __syncthreads();
  #pragma unroll
  for (int it = 0; it < 2; ++it) {
    int idx = it * 256 + tid;
    int dh = idx >> 3, tc = (idx & 7) * 8;
    bf16x8 v;
    #pragma unroll
    for (int j = 0; j < 8; ++j) v[j] = Tl[tc + j][dh];
    *(bf16x8*)&Vt[((size_t)bh * 64 + dh) * T_ + t0 + tc] = v;
  }
}

// ---------------- flash attention: r10 structure (measured 41.8us) ----------------
// Block = 512 threads. Waves 0-3 (group A): KV tiles [0, qt]; waves 4-7 (B):
// [qt+1, 2qt+1]. Partials merged through LDS. tau-trick PV (no shuffles).
// qt map pairs near-equal durations on a CU (r9/r10 lesson: co-resident
// blocks hide each other's latency; maximize the min of each pair).
// Grid (B*H, 16): id%8 = bh%8 keeps each head on one XCD (L2-resident KV).
__global__ __launch_bounds__(512) void attn_k(const bf16_t* __restrict__ Q,
                                              const bf16_t* __restrict__ K,
                                              const bf16_t* __restrict__ Vt,
                                              bf16_t* __restrict__ O) {
  const int bh = blockIdx.x, b = bh >> 4, h = bh & 15;
  const int yy = (int)blockIdx.y;
  const int qt = (yy < 8) ? (15 - 2 * yy) : (30 - 2 * yy);
  const int tid = threadIdx.x;

  __shared__ __align__(16) char smem[65536];

  const bf16_t* Kt0 = K + ((size_t)b * T_) * D_ + h * 64;
  const bf16_t* Vt0 = Vt + (size_t)bh * 64 * T_;

  const int lane = tid & 63, w = tid >> 6;
  const int wl = w & 3, wg = w >> 2;
  const int ln = lane & 31, hi = lane >> 5;
  const int tl = tid & 255;
  // tau: swap quads 1<->2 within each 16 (involution)
  const int tau = (ln & ~12) | (((ln & 4) << 1) | ((ln & 8) >> 1));
  char* sgbase = smem + ((tid >= 256) ? 32768 : 0);  // staging base (thread's group)
  char* cgbase = smem + wg * 32768;                  // compute base (wave's group)
  float* mo = (float*)smem;                          // merge: [4][64][33] f32
  float* ml = (float*)(smem + 33792);                // merge: [4][64][2]  f32

  const int q_abs = qt * 128 + wl * 32 + ln;
  bf16x8 qf[4];
  {
    const bf16_t* Qrow = Q + ((size_t)b * T_ + q_abs) * D_ + h * 64;
    #pragma unroll
    for (int ks = 0; ks < 4; ++ks)
      qf[ks] = *(const bf16x8*)(Qrow + ks * 16 + hi * 8);
  }

  f32x16 o0 = zero16(), o1 = zero16();   // O^T: rows=dh (0..31 / 32..63), col=q=ln
  float m = -1e30f, l = 0.f;

  const int jc    = qt + 1;              // iterations per group
  const int jd    = 2 * qt + (wl >> 1);  // my diagonal KV tile
  const int tbase = wg ? (qt + 1) : 0;   // group KV range start

#define STAGE8(BUF, TT)                                                       \
  {                                                                           \
    char* kd = sgbase + (BUF) * 8192;                                         \
    char* vd = sgbase + 16384 + (BUF) * 8192;                                 \
    _Pragma("unroll")                                                         \
    for (int it = 0; it < 2; ++it) {                                          \
      int c = it * 256 + tl;                                                  \
      int row = c >> 3, sl = c & 7;                                           \
      int slg = sl ^ (row & 7);                                               \
      async16(Kt0 + ((size_t)((TT) * 64 + row)) * D_ + slg * 8, kd + c * 16); \
      async16(Vt0 + (size_t)row * T_ + (TT) * 64 + slg * 8, vd + c * 16);     \
    }                                                                         \
  }

  // P regs are already in fragment order (tau-trick): 4 pk2, no shuffles.
#define PACK_PV8(PS, KS, VB)                                                  \
  {                                                                           \
    const int r0 = ((KS) & 1) * 8;                                            \
    u32x4 pw = {pk2((PS)[r0 + 0], (PS)[r0 + 1]),                              \
                pk2((PS)[r0 + 2], (PS)[r0 + 3]),                              \
                pk2((PS)[r0 + 4], (PS)[r0 + 5]),                              \
                pk2((PS)[r0 + 6], (PS)[r0 + 7])};                             \
    bf16x8 pb = __builtin_bit_cast(bf16x8, pw);                               \
    const int sg = (KS) * 2 + hi;                                             \
    int row = ln;                                                             \
    bf16x8 vf0 = *(const bf16x8*)((VB) + row * 64 + ((sg ^ (row & 7)) * 8));  \
    o0 = MFMA32(vf0, pb, o0);                                                 \
    row = 32 + ln;                                                            \
    bf16x8 vf1 = *(const bf16x8*)((VB) + row * 64 + ((sg ^ (row & 7)) * 8));  \
    o1 = MFMA32(vf1, pb, o1);                                                 \
  }

  STAGE8(0, tbase)
  int cur = 0;
  for (int j = 0; j < jc; ++j) {
    if (j + 1 < jc) {
      STAGE8(cur ^ 1, tbase + j + 1)
      asm volatile("s_waitcnt vmcnt(4)" ::: "memory");
    } else {
      asm volatile("s_waitcnt vmcnt(0)" ::: "memory");
    }
    __builtin_amdgcn_s_barrier();

    const int tt = tbase + j;
    if (tt <= jd) {
      const bf16_t* Kb = (const bf16_t*)(cgbase + cur * 8192);
      const bf16_t* Vb = (const bf16_t*)(cgbase + 16384 + cur * 8192);
      // S^T = K . Q^T with tau-permuted A rows: reg r holds P at
      // kv = (r&7) + 16*(r>>3) + 8*hi  (+32 for s1)
      f32x16 s0 = zero16(), s1 = zero16();
      __builtin_amdgcn_s_setprio(1);
      #pragma unroll
      for (int ks = 0; ks < 4; ++ks) {
        const int sg = ks * 2 + hi;
        int row = tau;
        bf16x8 kf0 = *(const bf16x8*)(Kb + row * 64 + ((sg ^ (row & 7)) * 8));
        s0 = MFMA32(kf0, qf[ks], s0);
        row = 32 + tau;
        bf16x8 kf1 = *(const bf16x8*)(Kb + row * 64 + ((sg ^ (row & 7)) * 8));
        s1 = MFMA32(kf1, qf[ks], s1);
      }
      __builtin_amdgcn_s_setprio(0);
      if (tt == jd) {
        const int kv0 = tt * 64;
        #pragma unroll
        for (int r = 0; r < 16; ++r) {
          const int pos = (r & 7) + 16 * (r >> 3) + 8 * hi;
          if (kv0 + pos      > q_abs) s0[r] = -3e38f;
          if (kv0 + 32 + pos > q_abs) s1[r] = -3e38f;
        }
      }
      // online softmax (log2 domain), tree reductions, defer-max
      float t[16];
      #pragma unroll
      for (int r = 0; r < 16; ++r) t[r] = fmaxf(s0[r], s1[r]);
      #pragma unroll
      for (int st = 8; st >= 1; st >>= 1)
        #pragma unroll
        for (int i = 0; i < st; ++i) t[i] = fmaxf(t[i], t[i + st]);
      float pmax = xswap_max(t[0]);
      if (!__all(pmax - m <= DEFER_THR)) {
        float mn   = fmaxf(m, pmax);
        float corr = EXP2(m - mn);
        m = mn;
        l *= corr;
        #pragma unroll
        for (int r = 0; r < 16; ++r) { o0[r] *= corr; o1[r] *= corr; }
      }
      float u[16];
      #pragma unroll
      for (int r = 0; r < 16; ++r) {
        float p0 = EXP2(s0[r] - m); s0[r] = p0;
        float p1 = EXP2(s1[r] - m); s1[r] = p1;
        u[r] = p0 + p1;
      }
      #pragma unroll
      for (int st = 8; st >= 1; st >>= 1)
        #pragma unroll
        for (int i = 0; i < st; ++i) u[i] += u[i + st];
      l += xswap_sum(u[0]);
      __builtin_amdgcn_s_setprio(1);
      PACK_PV8(s0, 0, Vb)
      PACK_PV8(s0, 1, Vb)
      PACK_PV8(s1, 2, Vb)
      PACK_PV8(s1, 3, Vb)
      __builtin_amdgcn_s_setprio(0);
    }
    __builtin_amdgcn_s_barrier();
    cur ^= 1;
  }

  // ---- merge group B partials into group A, then store ----
  if (wg == 1) {
    float* mop = mo + ((size_t)wl * 64 + lane) * 33;
    #pragma unroll
    for (int r = 0; r < 16; ++r) { mop[r] = o0[r]; mop[16 + r] = o1[r]; }
    float* mlp = ml + ((size_t)wl * 64 + lane) * 2;
    mlp[0] = m; mlp[1] = l;
  }
  __syncthreads();
  if (wg == 0) {
    const float* mop = mo + ((size_t)wl * 64 + lane) * 33;
    const float* mlp = ml + ((size_t)wl * 64 + lane) * 2;
    float mB = mlp[0], lB = mlp[1];
    float mS = fmaxf(m, mB);
    float cA = EXP2(m - mS), cB = EXP2(mB - mS);
    float lS = l * cA + lB * cB;
    float rl = 1.0f / lS;
    bf16_t* Orow = O + ((size_t)b * T_ + q_abs) * D_ + h * 64;
    #pragma unroll
    for (int g = 0; g < 4; ++g) {
      const int dh0 = 8 * g + 4 * hi;
      bf16x4 v0, v1;
      #pragma unroll
      for (int jj = 0; jj < 4; ++jj) {
        v0[jj] = (__bf16)((o0[4 * g + jj] * cA + mop[4 * g + jj] * cB) * rl);
        v1[jj] = (__bf16)((o1[4 * g + jj] * cA + mop[16 + 4 * g + jj] * cB) * rl);
      }
      *(bf16x4*)(Orow + dh0)      = v0;
      *(bf16x4*)(Orow + 32 + dh0) = v1;
    }
  }
#undef STAGE8
#undef PACK_PV8
}

// ---------------- launcher ----------------
extern "C" void kernel_launch(void* const* d_in, const int* in_sizes, int n_in,
                              void* d_out, int out_size, void* d_ws, size_t ws_size,
                              hipStream_t stream) {
  const float* x  = (const float*)d_in[0];
  const float* wq = (const float*)d_in[1];
  const float* wk = (const float*)d_in[2];
  const float* wv = (const float*)d_in[3];
  const float* wo = (const float*)d_in[4];
  float* out = (float*)d_out;

  char* ws = (char*)d_ws;
  bf16_t* xb  = (bf16_t*)(ws);                       // 8 MB
  bf16_t* wqb = (bf16_t*)(ws + (size_t)( 8 << 20));  // 2 MB each
  bf16_t* wkb = (bf16_t*)(ws + (size_t)(10 << 20));
  bf16_t* wvb = (bf16_t*)(ws + (size_t)(12 << 20));
  bf16_t* wob = (bf16_t*)(ws + (size_t)(14 << 20));
  bf16_t* Qb  = (bf16_t*)(ws + (size_t)(16 << 20));  // 8 MB
  bf16_t* Kb  = (bf16_t*)(ws + (size_t)(24 << 20));  // 8 MB
  bf16_t* Vb  = (bf16_t*)(ws + (size_t)(32 << 20));  // 8 MB
  bf16_t* Vtb = (bf16_t*)(ws + (size_t)(40 << 20));  // 8 MB
  bf16_t* Ob  = Vb;   // Vb dead after vt_k; attn output reuses its slot

  (void)in_sizes; (void)n_in; (void)out_size; (void)ws_size;

  cast_all_k<<<dim3(4096), 256, 0, stream>>>(x, wq, wk, wv, wo, xb, wqb);
  qkv_gemm_k<<<dim3(M_ / 128, D_ / 128, 3), 256, 0, stream>>>(xb, wqb, wkb, wvb, Qb, Kb, Vb);
  vt_k<<<dim3(T_ / 64, B_ * H_), 256, 0, stream>>>(Vb, Vtb);
  attn_k<<<dim3(B_ * H_, T_ / 128), 512, 0, stream>>>(Qb, Kb, Vtb, Ob);
  out_gemm_k<<<dim3(M_ / 128, D_ / 128), 256, 0, stream>>>(Ob, wob, out);
}

// Round 16
// 111.542 us; speedup vs baseline: 1.5474x; 1.0448x over previous
//
#include <hip/hip_runtime.h>
#include <hip/hip_bf16.h>
#include <cstdint>
#include <cstddef>

#define B_  2
#define T_  2048
#define D_  1024
#define H_  16
#define M_  (B_*T_)   // 4096 rows total

typedef __bf16 bf16_t;
typedef __attribute__((ext_vector_type(8))) __bf16 bf16x8;
typedef __attribute__((ext_vector_type(4))) __bf16 bf16x4;
typedef __attribute__((ext_vector_type(4))) float f32x4;
typedef __attribute__((ext_vector_type(16))) float f32x16;
typedef unsigned int u32;
typedef __attribute__((ext_vector_type(4))) u32 u32x4;

#define MFMA16(a,b,c) __builtin_amdgcn_mfma_f32_16x16x32_bf16(a,b,c,0,0,0)
#define MFMA32(a,b,c) __builtin_amdgcn_mfma_f32_32x32x16_bf16(a,b,c,0,0,0)
#define EXP2(x) __builtin_amdgcn_exp2f(x)

#define QSCALE 0.18033688011112042f
#define DEFER_THR 10.0f

__device__ inline void async16(const void* g, void* l) {
  __builtin_amdgcn_global_load_lds((const __attribute__((address_space(1))) void*)g,
                                   (__attribute__((address_space(3))) void*)l, 16, 0, 0);
}

__device__ __forceinline__ f32x16 zero16() {
  f32x16 z;
  #pragma unroll
  for (int i = 0; i < 16; ++i) z[i] = 0.f;
  return z;
}

__device__ __forceinline__ u32 pk2(float lo, float hi) {
  u32 a = __builtin_bit_cast(unsigned short, (__bf16)lo);
  u32 b = __builtin_bit_cast(unsigned short, (__bf16)hi);
  return a | (b << 16);
}
__device__ __forceinline__ float xswap_max(float x) {
  return fmaxf(x, __shfl_xor(x, 32));
}
__device__ __forceinline__ float xswap_sum(float x) {
  return x + __shfl_xor(x, 32);
}

// ---------------- fused cast kernel ----------------
__global__ __launch_bounds__(256) void cast_all_k(const float* __restrict__ x,
                                                  const float* __restrict__ wq,
                                                  const float* __restrict__ wk,
                                                  const float* __restrict__ wv,
                                                  const float* __restrict__ wo,
                                                  bf16_t* __restrict__ xb,
                                                  bf16_t* __restrict__ wbase) {
  int bid = blockIdx.x;
  const float* src;
  bf16_t* dst;
  float sc = 1.0f;
  int i;
  if (bid < 2048) {
    src = x; dst = xb; i = bid * 256 + threadIdx.x;
  } else {
    int wsel = (bid - 2048) >> 9;
    int wblk = (bid - 2048) & 511;
    src = wsel == 0 ? wq : wsel == 1 ? wk : wsel == 2 ? wv : wo;
    if (wsel == 0) sc = QSCALE;
    dst = wbase + (size_t)wsel * D_ * D_;
    i = wblk * 256 + threadIdx.x;
  }
  const float4* p = (const float4*)src + 2 * (size_t)i;
  float4 a = p[0], b = p[1];
  bf16x8 r = { (__bf16)(a.x*sc), (__bf16)(a.y*sc), (__bf16)(a.z*sc), (__bf16)(a.w*sc),
               (__bf16)(b.x*sc), (__bf16)(b.y*sc), (__bf16)(b.z*sc), (__bf16)(b.w*sc) };
  *((bf16x8*)dst + i) = r;
}

// ============ 256x256 BK=64 4-phase QKV GEMM (T2+T3+T4+T5) ============
// 512 threads = 8 waves (2M x 4N). Wave output 128x64 -> acc[8][4] f32x4.
// LDS 128KB dynamic: [2 buf][A 256x64 swz 32KB | B 256x64 swz 32KB].
// Swizzle: byte_col ^= (row&7)<<4 (involution; stage-source + read side).
// SYNC PROTOCOL (r15 race fix): phase 0 is barrier1 -> stage -> vmcnt(2)
// -> barrier2. The vmcnt must come BEFORE the barrier that gates reads:
// vmcnt only drains the ISSUING wave's loads; barrier2 makes that a
// block-wide guarantee (each wave drained its own before arriving).
// barrier1 closes the WAR window (reads of buf (t+1)&1 in tile t-1 end
// before any wave writes it). Phases 1-3: single barrier + stage + MFMA.
__global__ __launch_bounds__(512) void qkv8_k(const bf16_t* __restrict__ xb,
                                              const bf16_t* __restrict__ wqkv,
                                              bf16_t* __restrict__ Qbase) {
  extern __shared__ __align__(16) char lds[];
  const int z = blockIdx.z;
  const bf16_t* W = wqkv + (size_t)z * D_ * D_;
  bf16_t* C = Qbase + (size_t)z * M_ * D_;
  const int brow = blockIdx.x * 256, bcol = blockIdx.y * 256;

  const int tid = threadIdx.x;
  const int lane = tid & 63, w = tid >> 6;
  const int wm = w >> 2, wn = w & 3;
  const int lo = lane & 15, hi4 = lane >> 4;
  const int swz = (lo & 7) << 4;       // read-side swizzle (row&7 == lo&7)

  f32x4 acc[8][4];
  #pragma unroll
  for (int q = 0; q < 8; ++q)
    #pragma unroll
    for (int f = 0; f < 4; ++f) acc[q][f] = (f32x4){0.f, 0.f, 0.f, 0.f};

  // H: 0 = A rows 0-127, 1 = A rows 128-255, 2 = B rows 0-127, 3 = B rows 128-255
#define QSTAGE(T, H)                                                          \
  {                                                                           \
    const bf16_t* src = ((H) < 2) ? (xb + (size_t)brow * D_)                  \
                                  : (W + (size_t)bcol * D_);                  \
    const int rb = ((H) & 1) * 128;                                           \
    char* dst = lds + ((T) & 1) * 65536 + (((H) < 2) ? 0 : 32768) + rb * 128; \
    const int kt = (T) * 64;                                                  \
    _Pragma("unroll")                                                         \
    for (int i2 = 0; i2 < 2; ++i2) {                                          \
      int idx = i2 * 512 + tid;                                               \
      int row = idx >> 3;                                                     \
      int cb = ((idx & 7) * 16) ^ ((row & 7) << 4);                           \
      async16(src + (size_t)(rb + row) * D_ + kt + (cb >> 1), dst + idx * 16);\
    }                                                                         \
  }

  // prologue: tile 0 fully staged
  QSTAGE(0, 0) QSTAGE(0, 1) QSTAGE(0, 2) QSTAGE(0, 3)

  const int nT = D_ / 64;   // 16 K-tiles
  for (int t = 0; t < nT; ++t) {
    const char* Ab = lds + (t & 1) * 65536;
    const char* Bb = Ab + 32768;
    bf16x8 afr[2][4], bfr[2][2];

    // ---- phase 0: A-low + B fn0-1; acc[0..3][0..1] ----
    __builtin_amdgcn_s_barrier();          // reads of buf (t+1)&1 (tile t-1) done
    if (t + 1 < nT) {
      QSTAGE(t + 1, 0)
      asm volatile("s_waitcnt vmcnt(2)" ::: "memory");   // own tile-t loads done
    } else {
      asm volatile("s_waitcnt vmcnt(0)" ::: "memory");
    }
    __builtin_amdgcn_s_barrier();          // ALL waves' tile-t loads in LDS
    #pragma unroll
    for (int ks = 0; ks < 2; ++ks) {
      #pragma unroll
      for (int q = 0; q < 4; ++q) {
        int row = wm * 128 + q * 16 + lo;
        afr[ks][q] = *(const bf16x8*)(Ab + row * 128 + ((ks * 64 + hi4 * 16) ^ swz));
      }
      #pragma unroll
      for (int f = 0; f < 2; ++f) {
        int row = wn * 64 + f * 16 + lo;
        bfr[ks][f] = *(const bf16x8*)(Bb + row * 128 + ((ks * 64 + hi4 * 16) ^ swz));
      }
    }
    __builtin_amdgcn_s_setprio(1);
    #pragma unroll
    for (int q = 0; q < 4; ++q)
      #pragma unroll
      for (int f = 0; f < 2; ++f)
        #pragma unroll
        for (int ks = 0; ks < 2; ++ks)
          acc[q][f] = MFMA16(afr[ks][q], bfr[ks][f], acc[q][f]);
    __builtin_amdgcn_s_setprio(0);

    // ---- phase 1: B fn2-3; acc[0..3][2..3] (A held) ----
    __builtin_amdgcn_s_barrier();
    if (t + 1 < nT) QSTAGE(t + 1, 1)
    #pragma unroll
    for (int ks = 0; ks < 2; ++ks)
      #pragma unroll
      for (int f = 0; f < 2; ++f) {
        int row = wn * 64 + (2 + f) * 16 + lo;
        bfr[ks][f] = *(const bf16x8*)(Bb + row * 128 + ((ks * 64 + hi4 * 16) ^ swz));
      }
    __builtin_amdgcn_s_setprio(1);
    #pragma unroll
    for (int q = 0; q < 4; ++q)
      #pragma unroll
      for (int f = 0; f < 2; ++f)
        #pragma unroll
        for (int ks = 0; ks < 2; ++ks)
          acc[q][2 + f] = MFMA16(afr[ks][q], bfr[ks][f], acc[q][2 + f]);
    __builtin_amdgcn_s_setprio(0);

    // ---- phase 2: A-high; acc[4..7][2..3] (B held) ----
    __builtin_amdgcn_s_barrier();
    if (t + 1 < nT) QSTAGE(t + 1, 2)
    #pragma unroll
    for (int ks = 0; ks < 2; ++ks)
      #pragma unroll
      for (int q = 0; q < 4; ++q) {
        int row = wm * 128 + 64 + q * 16 + lo;
        afr[ks][q] = *(const bf16x8*)(Ab + row * 128 + ((ks * 64 + hi4 * 16) ^ swz));
      }
    __builtin_amdgcn_s_setprio(1);
    #pragma unroll
    for (int q = 0; q < 4; ++q)
      #pragma unroll
      for (int f = 0; f < 2; ++f)
        #pragma unroll
        for (int ks = 0; ks < 2; ++ks)
          acc[4 + q][2 + f] = MFMA16(afr[ks][q], bfr[ks][f], acc[4 + q][2 + f]);
    __builtin_amdgcn_s_setprio(0);

    // ---- phase 3: B fn0-1 again; acc[4..7][0..1] (A held) ----
    __builtin_amdgcn_s_barrier();
    if (t + 1 < nT) QSTAGE(t + 1, 3)
    #pragma unroll
    for (int ks = 0; ks < 2; ++ks)
      #pragma unroll
      for (int f = 0; f < 2; ++f) {
        int row = wn * 64 + f * 16 + lo;
        bfr[ks][f] = *(const bf16x8*)(Bb + row * 128 + ((ks * 64 + hi4 * 16) ^ swz));
      }
    __builtin_amdgcn_s_setprio(1);
    #pragma unroll
    for (int q = 0; q < 4; ++q)
      #pragma unroll
      for (int f = 0; f < 2; ++f)
        #pragma unroll
        for (int ks = 0; ks < 2; ++ks)
          acc[4 + q][f] = MFMA16(afr[ks][q], bfr[ks][f], acc[4 + q][f]);
    __builtin_amdgcn_s_setprio(0);
  }
#undef QSTAGE

  // epilogue: frag Q: row = wm*128 + (Q>>2)*64 + (Q&3)*16 + hi4*4 + i
  #pragma unroll
  for (int Q = 0; Q < 8; ++Q)
    #pragma unroll
    for (int f = 0; f < 4; ++f)
      #pragma unroll
      for (int i = 0; i < 4; ++i) {
        int row = brow + wm * 128 + (Q >> 2) * 64 + (Q & 3) * 16 + hi4 * 4 + i;
        int col = bcol + wn * 64 + f * 16 + lo;
        C[(size_t)row * D_ + col] = (bf16_t)acc[Q][f][i];
      }
}

// ---------------- 128x128 NT GEMM, double-buffered (out projection) ----------------
template<typename OUT>
__device__ __forceinline__ void gemm_bt_128db(const bf16_t* __restrict__ A,
                                              const bf16_t* __restrict__ W,
                                              OUT* __restrict__ C,
                                              int Kdim, int ldc_n, int brow, int bcol) {
  __shared__ __align__(16) bf16_t As[2][128 * 32];
  __shared__ __align__(16) bf16_t Bs[2][128 * 32];
  const int lane = threadIdx.x & 63;
  const int w    = threadIdx.x >> 6;
  const int lo   = lane & 15, hi = lane >> 4;
  const int wr   = w >> 1, wc = w & 1;

  f32x4 acc[4][4];
  #pragma unroll
  for (int i = 0; i < 4; ++i)
    #pragma unroll
    for (int j = 0; j < 4; ++j) acc[i][j] = (f32x4){0.f, 0.f, 0.f, 0.f};

#define GSTAGE(BUF, KT)                                                        \
  {                                                                            \
    _Pragma("unroll")                                                          \
    for (int i = 0; i < 2; ++i) {                                              \
      int chunk = w * 2 + i;                                                   \
      int r = chunk * 16 + (lane >> 2);                                        \
      int c = (lane & 3) * 8;                                                  \
      async16(A + (size_t)(brow + r) * Kdim + (KT) + c,                        \
              (char*)As[BUF] + chunk * 1024);                                  \
      async16(W + (size_t)(bcol + r) * Kdim + (KT) + c,                        \
              (char*)Bs[BUF] + chunk * 1024);                                  \
    }                                                                          \
  }

  const int nK = Kdim >> 5;
  GSTAGE(0, 0)
  int cur = 0;
  for (int ki = 0; ki < nK; ++ki) {
    if (ki + 1 < nK) {
      GSTAGE(cur ^ 1, (ki + 1) * 32)
      asm volatile("s_waitcnt vmcnt(4)" ::: "memory");
    } else {
      asm volatile("s_waitcnt vmcnt(0)" ::: "memory");
    }
    __builtin_amdgcn_s_barrier();
    bf16x8 af[4], bfr[4];
    #pragma unroll
    for (int mi = 0; mi < 4; ++mi)
      af[mi] = *(const bf16x8*)&As[cur][(wr * 64 + mi * 16 + lo) * 32 + hi * 8];
    #pragma unroll
    for (int ni = 0; ni < 4; ++ni)
      bfr[ni] = *(const bf16x8*)&Bs[cur][(wc * 64 + ni * 16 + lo) * 32 + hi * 8];
    #pragma unroll
    for (int mi = 0; mi < 4; ++mi)
      #pragma unroll
      for (int ni = 0; ni < 4; ++ni)
        acc[mi][ni] = MFMA16(af[mi], bfr[ni], acc[mi][ni]);
    __builtin_amdgcn_s_barrier();
    cur ^= 1;
  }
#undef GSTAGE

  #pragma unroll
  for (int mi = 0; mi < 4; ++mi)
    #pragma unroll
    for (int ni = 0; ni < 4; ++ni)
      #pragma unroll
      for (int i = 0; i < 4; ++i) {
        int row = brow + wr * 64 + mi * 16 + hi * 4 + i;
        int col = bcol + wc * 64 + ni * 16 + lo;
        C[(size_t)row * ldc_n + col] = (OUT)acc[mi][ni][i];
      }
}

__global__ __launch_bounds__(256) void out_gemm_k(const bf16_t* __restrict__ O,
                                                  const bf16_t* __restrict__ wob,
                                                  float* __restrict__ Y) {
  gemm_bt_128db<float>(O, wob, Y, D_, D_, blockIdx.x * 128, blockIdx.y * 128);
}

// ---------------- V transpose: V(B,T,D) -> Vt[(b*H+h)*64+dh][T] ----------------
__global__ __launch_bounds__(256) void vt_k(const bf16_t* __restrict__ V,
                                            bf16_t* __restrict__ Vt) {
  __shared__ bf16_t Tl[64][68];
  const int t0 = blockIdx.x * 64;
  const int bh = blockIdx.y, b = bh >> 4, h = bh & 15;
  const int tid = threadIdx.x;
  #pragma unroll
  for (int it = 0; it < 2; ++it) {
    int idx = it * 256 + tid;
    int r = idx >> 3, c8 = (idx & 7) * 8;
    *(bf16x8*)&Tl[r][c8] = *(const bf16x8*)&V[((size_t)(b * T_ + t0 + r)) * D_ + h * 64 + c8];
  }
  __syncthreads();
  #pragma unroll
  for (int it = 0; it < 2; ++it) {
    int idx = it * 256 + tid;
    int dh = idx >> 3, tc = (idx & 7) * 8;
    bf16x8 v;
    #pragma unroll
    for (int j = 0; j < 8; ++j) v[j] = Tl[tc + j][dh];
    *(bf16x8*)&Vt[((size_t)bh * 64 + dh) * T_ + t0 + tc] = v;
  }
}

// ---------------- flash attention: r10 structure (measured 41.8us) ----------------
__global__ __launch_bounds__(512) void attn_k(const bf16_t* __restrict__ Q,
                                              const bf16_t* __restrict__ K,
                                              const bf16_t* __restrict__ Vt,
                                              bf16_t* __restrict__ O) {
  const int bh = blockIdx.x, b = bh >> 4, h = bh & 15;
  const int yy = (int)blockIdx.y;
  const int qt = (yy < 8) ? (15 - 2 * yy) : (30 - 2 * yy);
  const int tid = threadIdx.x;

  __shared__ __align__(16) char smem[65536];

  const bf16_t* Kt0 = K + ((size_t)b * T_) * D_ + h * 64;
  const bf16_t* Vt0 = Vt + (size_t)bh * 64 * T_;

  const int lane = tid & 63, w = tid >> 6;
  const int wl = w & 3, wg = w >> 2;
  const int ln = lane & 31, hi = lane >> 5;
  const int tl = tid & 255;
  const int tau = (ln & ~12) | (((ln & 4) << 1) | ((ln & 8) >> 1));
  char* sgbase = smem + ((tid >= 256) ? 32768 : 0);
  char* cgbase = smem + wg * 32768;
  float* mo = (float*)smem;
  float* ml = (float*)(smem + 33792);

  const int q_abs = qt * 128 + wl * 32 + ln;
  bf16x8 qf[4];
  {
    const bf16_t* Qrow = Q + ((size_t)b * T_ + q_abs) * D_ + h * 64;
    #pragma unroll
    for (int ks = 0; ks < 4; ++ks)
      qf[ks] = *(const bf16x8*)(Qrow + ks * 16 + hi * 8);
  }

  f32x16 o0 = zero16(), o1 = zero16();
  float m = -1e30f, l = 0.f;

  const int jc    = qt + 1;
  const int jd    = 2 * qt + (wl >> 1);
  const int tbase = wg ? (qt + 1) : 0;

#define STAGE8(BUF, TT)                                                       \
  {                                                                           \
    char* kd = sgbase + (BUF) * 8192;                                         \
    char* vd = sgbase + 16384 + (BUF) * 8192;                                 \
    _Pragma("unroll")                                                         \
    for (int it = 0; it < 2; ++it) {                                          \
      int c = it * 256 + tl;                                                  \
      int row = c >> 3, sl = c & 7;                                           \
      int slg = sl ^ (row & 7);                                               \
      async16(Kt0 + ((size_t)((TT) * 64 + row)) * D_ + slg * 8, kd + c * 16); \
      async16(Vt0 + (size_t)row * T_ + (TT) * 64 + slg * 8, vd + c * 16);     \
    }                                                                         \
  }

#define PACK_PV8(PS, KS, VB)                                                  \
  {                                                                           \
    const int r0 = ((KS) & 1) * 8;                                            \
    u32x4 pw = {pk2((PS)[r0 + 0], (PS)[r0 + 1]),                              \
                pk2((PS)[r0 + 2], (PS)[r0 + 3]),                              \
                pk2((PS)[r0 + 4], (PS)[r0 + 5]),                              \
                pk2((PS)[r0 + 6], (PS)[r0 + 7])};                             \
    bf16x8 pb = __builtin_bit_cast(bf16x8, pw);                               \
    const int sg = (KS) * 2 + hi;                                             \
    int row = ln;                                                             \
    bf16x8 vf0 = *(const bf16x8*)((VB) + row * 64 + ((sg ^ (row & 7)) * 8));  \
    o0 = MFMA32(vf0, pb, o0);                                                 \
    row = 32 + ln;                                                            \
    bf16x8 vf1 = *(const bf16x8*)((VB) + row * 64 + ((sg ^ (row & 7)) * 8));  \
    o1 = MFMA32(vf1, pb, o1);                                                 \
  }

  STAGE8(0, tbase)
  int cur = 0;
  for (int j = 0; j < jc; ++j) {
    if (j + 1 < jc) {
      STAGE8(cur ^ 1, tbase + j + 1)
      asm volatile("s_waitcnt vmcnt(4)" ::: "memory");
    } else {
      asm volatile("s_waitcnt vmcnt(0)" ::: "memory");
    }
    __builtin_amdgcn_s_barrier();

    const int tt = tbase + j;
    if (tt <= jd) {
      const bf16_t* Kb = (const bf16_t*)(cgbase + cur * 8192);
      const bf16_t* Vb = (const bf16_t*)(cgbase + 16384 + cur * 8192);
      f32x16 s0 = zero16(), s1 = zero16();
      __builtin_amdgcn_s_setprio(1);
      #pragma unroll
      for (int ks = 0; ks < 4; ++ks) {
        const int sg = ks * 2 + hi;
        int row = tau;
        bf16x8 kf0 = *(const bf16x8*)(Kb + row * 64 + ((sg ^ (row & 7)) * 8));
        s0 = MFMA32(kf0, qf[ks], s0);
        row = 32 + tau;
        bf16x8 kf1 = *(const bf16x8*)(Kb + row * 64 + ((sg ^ (row & 7)) * 8));
        s1 = MFMA32(kf1, qf[ks], s1);
      }
      __builtin_amdgcn_s_setprio(0);
      if (tt == jd) {
        const int kv0 = tt * 64;
        #pragma unroll
        for (int r = 0; r < 16; ++r) {
          const int pos = (r & 7) + 16 * (r >> 3) + 8 * hi;
          if (kv0 + pos      > q_abs) s0[r] = -3e38f;
          if (kv0 + 32 + pos > q_abs) s1[r] = -3e38f;
        }
      }
      float t[16];
      #pragma unroll
      for (int r = 0; r < 16; ++r) t[r] = fmaxf(s0[r], s1[r]);
      #pragma unroll
      for (int st = 8; st >= 1; st >>= 1)
        #pragma unroll
        for (int i = 0; i < st; ++i) t[i] = fmaxf(t[i], t[i + st]);
      float pmax = xswap_max(t[0]);
      if (!__all(pmax - m <= DEFER_THR)) {
        float mn   = fmaxf(m, pmax);
        float corr = EXP2(m - mn);
        m = mn;
        l *= corr;
        #pragma unroll
        for (int r = 0; r < 16; ++r) { o0[r] *= corr; o1[r] *= corr; }
      }
      float u[16];
      #pragma unroll
      for (int r = 0; r < 16; ++r) {
        float p0 = EXP2(s0[r] - m); s0[r] = p0;
        float p1 = EXP2(s1[r] - m); s1[r] = p1;
        u[r] = p0 + p1;
      }
      #pragma unroll
      for (int st = 8; st >= 1; st >>= 1)
        #pragma unroll
        for (int i = 0; i < st; ++i) u[i] += u[i + st];
      l += xswap_sum(u[0]);
      __builtin_amdgcn_s_setprio(1);
      PACK_PV8(s0, 0, Vb)
      PACK_PV8(s0, 1, Vb)
      PACK_PV8(s1, 2, Vb)
      PACK_PV8(s1, 3, Vb)
      __builtin_amdgcn_s_setprio(0);
    }
    __builtin_amdgcn_s_barrier();
    cur ^= 1;
  }

  if (wg == 1) {
    float* mop = mo + ((size_t)wl * 64 + lane) * 33;
    #pragma unroll
    for (int r = 0; r < 16; ++r) { mop[r] = o0[r]; mop[16 + r] = o1[r]; }
    float* mlp = ml + ((size_t)wl * 64 + lane) * 2;
    mlp[0] = m; mlp[1] = l;
  }
  __syncthreads();
  if (wg == 0) {
    const float* mop = mo + ((size_t)wl * 64 + lane) * 33;
    const float* mlp = ml + ((size_t)wl * 64 + lane) * 2;
    float mB = mlp[0], lB = mlp[1];
    float mS = fmaxf(m, mB);
    float cA = EXP2(m - mS), cB = EXP2(mB - mS);
    float lS = l * cA + lB * cB;
    float rl = 1.0f / lS;
    bf16_t* Orow = O + ((size_t)b * T_ + q_abs) * D_ + h * 64;
    #pragma unroll
    for (int g = 0; g < 4; ++g) {
      const int dh0 = 8 * g + 4 * hi;
      bf16x4 v0, v1;
      #pragma unroll
      for (int jj = 0; jj < 4; ++jj) {
        v0[jj] = (__bf16)((o0[4 * g + jj] * cA + mop[4 * g + jj] * cB) * rl);
        v1[jj] = (__bf16)((o1[4 * g + jj] * cA + mop[16 + 4 * g + jj] * cB) * rl);
      }
      *(bf16x4*)(Orow + dh0)      = v0;
      *(bf16x4*)(Orow + 32 + dh0) = v1;
    }
  }
#undef STAGE8
#undef PACK_PV8
}

// ---------------- launcher ----------------
extern "C" void kernel_launch(void* const* d_in, const int* in_sizes, int n_in,
                              void* d_out, int out_size, void* d_ws, size_t ws_size,
                              hipStream_t stream) {
  const float* x  = (const float*)d_in[0];
  const float* wq = (const float*)d_in[1];
  const float* wk = (const float*)d_in[2];
  const float* wv = (const float*)d_in[3];
  const float* wo = (const float*)d_in[4];
  float* out = (float*)d_out;

  char* ws = (char*)d_ws;
  bf16_t* xb  = (bf16_t*)(ws);                       // 8 MB
  bf16_t* wqb = (bf16_t*)(ws + (size_t)( 8 << 20));  // 2 MB each (contiguous qkv+o)
  bf16_t* wob = (bf16_t*)(ws + (size_t)(14 << 20));
  bf16_t* Qb  = (bf16_t*)(ws + (size_t)(16 << 20));  // 8 MB each, Q/K/V contiguous
  bf16_t* Kb  = (bf16_t*)(ws + (size_t)(24 << 20));
  bf16_t* Vb  = (bf16_t*)(ws + (size_t)(32 << 20));
  bf16_t* Vtb = (bf16_t*)(ws + (size_t)(40 << 20));
  bf16_t* Ob  = Vb;   // Vb dead after vt_k

  (void)in_sizes; (void)n_in; (void)out_size; (void)ws_size;

  hipFuncSetAttribute((const void*)qkv8_k,
                      hipFuncAttributeMaxDynamicSharedMemorySize, 131072);

  cast_all_k<<<dim3(4096), 256, 0, stream>>>(x, wq, wk, wv, wo, xb, wqb);
  qkv8_k<<<dim3(M_ / 256, D_ / 256, 3), 512, 131072, stream>>>(xb, wqb, Qb);
  vt_k<<<dim3(T_ / 64, B_ * H_), 256, 0, stream>>>(Vb, Vtb);
  attn_k<<<dim3(B_ * H_, T_ / 128), 512, 0, stream>>>(Qb, Kb, Vtb, Ob);
  out_gemm_k<<<dim3(M_ / 128, D_ / 128), 256, 0, stream>>>(Ob, wob, out);
}

// Round 17
// 111.307 us; speedup vs baseline: 1.5506x; 1.0021x over previous
//
#include <hip/hip_runtime.h>
#include <hip/hip_bf16.h>
#include <cstdint>
#include <cstddef>

#define B_  2
#define T_  2048
#define D_  1024
#define H_  16
#define M_  (B_*T_)   // 4096 rows total

typedef __bf16 bf16_t;
typedef __attribute__((ext_vector_type(8))) __bf16 bf16x8;
typedef __attribute__((ext_vector_type(4))) __bf16 bf16x4;
typedef __attribute__((ext_vector_type(4))) float f32x4;
typedef __attribute__((ext_vector_type(16))) float f32x16;
typedef unsigned int u32;
typedef __attribute__((ext_vector_type(4))) u32 u32x4;

#define MFMA16(a,b,c) __builtin_amdgcn_mfma_f32_16x16x32_bf16(a,b,c,0,0,0)
#define MFMA32(a,b,c) __builtin_amdgcn_mfma_f32_32x32x16_bf16(a,b,c,0,0,0)
#define EXP2(x) __builtin_amdgcn_exp2f(x)

#define QSCALE 0.18033688011112042f
#define DEFER_THR 10.0f

__device__ inline void async16(const void* g, void* l) {
  __builtin_amdgcn_global_load_lds((const __attribute__((address_space(1))) void*)g,
                                   (__attribute__((address_space(3))) void*)l, 16, 0, 0);
}

__device__ __forceinline__ f32x16 zero16() {
  f32x16 z;
  #pragma unroll
  for (int i = 0; i < 16; ++i) z[i] = 0.f;
  return z;
}

__device__ __forceinline__ u32 pk2(float lo, float hi) {
  u32 a = __builtin_bit_cast(unsigned short, (__bf16)lo);
  u32 b = __builtin_bit_cast(unsigned short, (__bf16)hi);
  return a | (b << 16);
}
__device__ __forceinline__ float xswap_max(float x) {
  return fmaxf(x, __shfl_xor(x, 32));
}
__device__ __forceinline__ float xswap_sum(float x) {
  return x + __shfl_xor(x, 32);
}

// ---------------- fused cast kernel ----------------
__global__ __launch_bounds__(256) void cast_all_k(const float* __restrict__ x,
                                                  const float* __restrict__ wq,
                                                  const float* __restrict__ wk,
                                                  const float* __restrict__ wv,
                                                  const float* __restrict__ wo,
                                                  bf16_t* __restrict__ xb,
                                                  bf16_t* __restrict__ wbase) {
  int bid = blockIdx.x;
  const float* src;
  bf16_t* dst;
  float sc = 1.0f;
  int i;
  if (bid < 2048) {
    src = x; dst = xb; i = bid * 256 + threadIdx.x;
  } else {
    int wsel = (bid - 2048) >> 9;
    int wblk = (bid - 2048) & 511;
    src = wsel == 0 ? wq : wsel == 1 ? wk : wsel == 2 ? wv : wo;
    if (wsel == 0) sc = QSCALE;
    dst = wbase + (size_t)wsel * D_ * D_;
    i = wblk * 256 + threadIdx.x;
  }
  const float4* p = (const float4*)src + 2 * (size_t)i;
  float4 a = p[0], b = p[1];
  bf16x8 r = { (__bf16)(a.x*sc), (__bf16)(a.y*sc), (__bf16)(a.z*sc), (__bf16)(a.w*sc),
               (__bf16)(b.x*sc), (__bf16)(b.y*sc), (__bf16)(b.z*sc), (__bf16)(b.w*sc) };
  *((bf16x8*)dst + i) = r;
}

// ============ 256x256 BK=64 QKV GEMM, minimal-sync pipeline ============
// 512 threads = 8 waves (2M x 4N). Wave output 128x64 -> acc[8][4] f32x4.
// LDS 128KB dynamic: [2 buf][A 256x64 swz 32KB | B 256x64 swz 32KB].
// Swizzle: byte_col ^= (row&7)<<4 (involution; stage-source + read side).
// SYNC (r17): per K-tile, ONE vmcnt + TWO barriers (was 4 vmcnt + 5 bar):
//   [stage all 4 half-tiles of t+1]  -> 8 loads/thread to buf[(t+1)&1]
//   vmcnt(8)   -> drains this thread's 8 tile-t loads (issued last iter)
//   barrier    -> block-wide RAW: buf[t&1] fully in LDS
//   [all ds_reads + 64 MFMA, register-reusing sub-blocks, no setprio
//    (m190: lockstep GEMM, T5 null-to-negative)]
//   barrier    -> WAR: reads of buf[(t+1)&1]... wait: reads are of buf[t&1];
//                this barrier orders reads-done before next iter's stage of
//                buf[t&1] (= (t+2)&1). Verified ledger in r17 notes.
__global__ __launch_bounds__(512) void qkv8_k(const bf16_t* __restrict__ xb,
                                              const bf16_t* __restrict__ wqkv,
                                              bf16_t* __restrict__ Qbase) {
  extern __shared__ __align__(16) char lds[];
  const int z = blockIdx.z;
  const bf16_t* W = wqkv + (size_t)z * D_ * D_;
  bf16_t* C = Qbase + (size_t)z * M_ * D_;
  const int brow = blockIdx.x * 256, bcol = blockIdx.y * 256;

  const int tid = threadIdx.x;
  const int lane = tid & 63, w = tid >> 6;
  const int wm = w >> 2, wn = w & 3;
  const int lo = lane & 15, hi4 = lane >> 4;
  const int swz = (lo & 7) << 4;       // read-side swizzle (row&7 == lo&7)

  f32x4 acc[8][4];
  #pragma unroll
  for (int q = 0; q < 8; ++q)
    #pragma unroll
    for (int f = 0; f < 4; ++f) acc[q][f] = (f32x4){0.f, 0.f, 0.f, 0.f};

  // H: 0 = A rows 0-127, 1 = A rows 128-255, 2 = B rows 0-127, 3 = B rows 128-255
#define QSTAGE(T, H)                                                          \
  {                                                                           \
    const bf16_t* src = ((H) < 2) ? (xb + (size_t)brow * D_)                  \
                                  : (W + (size_t)bcol * D_);                  \
    const int rb = ((H) & 1) * 128;                                           \
    char* dst = lds + ((T) & 1) * 65536 + (((H) < 2) ? 0 : 32768) + rb * 128; \
    const int kt = (T) * 64;                                                  \
    _Pragma("unroll")                                                         \
    for (int i2 = 0; i2 < 2; ++i2) {                                          \
      int idx = i2 * 512 + tid;                                               \
      int row = idx >> 3;                                                     \
      int cb = ((idx & 7) * 16) ^ ((row & 7) << 4);                           \
      async16(src + (size_t)(rb + row) * D_ + kt + (cb >> 1), dst + idx * 16);\
    }                                                                         \
  }

  // prologue: tile 0 fully staged
  QSTAGE(0, 0) QSTAGE(0, 1) QSTAGE(0, 2) QSTAGE(0, 3)

  const int nT = D_ / 64;   // 16 K-tiles
  for (int t = 0; t < nT; ++t) {
    const char* Ab = lds + (t & 1) * 65536;
    const char* Bb = Ab + 32768;
    bf16x8 afr[2][4], bfr[2][2];

    if (t + 1 < nT) {
      QSTAGE(t + 1, 0) QSTAGE(t + 1, 1) QSTAGE(t + 1, 2) QSTAGE(t + 1, 3)
      asm volatile("s_waitcnt vmcnt(8)" ::: "memory");   // tile-t loads done (own)
    } else {
      asm volatile("s_waitcnt vmcnt(0)" ::: "memory");
    }
    __builtin_amdgcn_s_barrier();          // block-wide: tile-t fully in LDS

    // ---- sub-block 0: A-low + B fn0-1 -> acc[0..3][0..1] ----
    #pragma unroll
    for (int ks = 0; ks < 2; ++ks) {
      #pragma unroll
      for (int q = 0; q < 4; ++q) {
        int row = wm * 128 + q * 16 + lo;
        afr[ks][q] = *(const bf16x8*)(Ab + row * 128 + ((ks * 64 + hi4 * 16) ^ swz));
      }
      #pragma unroll
      for (int f = 0; f < 2; ++f) {
        int row = wn * 64 + f * 16 + lo;
        bfr[ks][f] = *(const bf16x8*)(Bb + row * 128 + ((ks * 64 + hi4 * 16) ^ swz));
      }
    }
    #pragma unroll
    for (int q = 0; q < 4; ++q)
      #pragma unroll
      for (int f = 0; f < 2; ++f)
        #pragma unroll
        for (int ks = 0; ks < 2; ++ks)
          acc[q][f] = MFMA16(afr[ks][q], bfr[ks][f], acc[q][f]);

    // ---- sub-block 1: B fn2-3 -> acc[0..3][2..3] (A held) ----
    #pragma unroll
    for (int ks = 0; ks < 2; ++ks)
      #pragma unroll
      for (int f = 0; f < 2; ++f) {
        int row = wn * 64 + (2 + f) * 16 + lo;
        bfr[ks][f] = *(const bf16x8*)(Bb + row * 128 + ((ks * 64 + hi4 * 16) ^ swz));
      }
    #pragma unroll
    for (int q = 0; q < 4; ++q)
      #pragma unroll
      for (int f = 0; f < 2; ++f)
        #pragma unroll
        for (int ks = 0; ks < 2; ++ks)
          acc[q][2 + f] = MFMA16(afr[ks][q], bfr[ks][f], acc[q][2 + f]);

    // ---- sub-block 2: A-high -> acc[4..7][2..3] (B held) ----
    #pragma unroll
    for (int ks = 0; ks < 2; ++ks)
      #pragma unroll
      for (int q = 0; q < 4; ++q) {
        int row = wm * 128 + 64 + q * 16 + lo;
        afr[ks][q] = *(const bf16x8*)(Ab + row * 128 + ((ks * 64 + hi4 * 16) ^ swz));
      }
    #pragma unroll
    for (int q = 0; q < 4; ++q)
      #pragma unroll
      for (int f = 0; f < 2; ++f)
        #pragma unroll
        for (int ks = 0; ks < 2; ++ks)
          acc[4 + q][2 + f] = MFMA16(afr[ks][q], bfr[ks][f], acc[4 + q][2 + f]);

    // ---- sub-block 3: B fn0-1 again -> acc[4..7][0..1] (A held) ----
    #pragma unroll
    for (int ks = 0; ks < 2; ++ks)
      #pragma unroll
      for (int f = 0; f < 2; ++f) {
        int row = wn * 64 + f * 16 + lo;
        bfr[ks][f] = *(const bf16x8*)(Bb + row * 128 + ((ks * 64 + hi4 * 16) ^ swz));
      }
    #pragma unroll
    for (int q = 0; q < 4; ++q)
      #pragma unroll
      for (int f = 0; f < 2; ++f)
        #pragma unroll
        for (int ks = 0; ks < 2; ++ks)
          acc[4 + q][f] = MFMA16(afr[ks][q], bfr[ks][f], acc[4 + q][f]);

    __builtin_amdgcn_s_barrier();   // WAR: reads of buf[t&1] done before its next stage
  }
#undef QSTAGE

  // epilogue: frag Q: row = wm*128 + (Q>>2)*64 + (Q&3)*16 + hi4*4 + i
  #pragma unroll
  for (int Q = 0; Q < 8; ++Q)
    #pragma unroll
    for (int f = 0; f < 4; ++f)
      #pragma unroll
      for (int i = 0; i < 4; ++i) {
        int row = brow + wm * 128 + (Q >> 2) * 64 + (Q & 3) * 16 + hi4 * 4 + i;
        int col = bcol + wn * 64 + f * 16 + lo;
        C[(size_t)row * D_ + col] = (bf16_t)acc[Q][f][i];
      }
}

// ---------------- 128x128 NT GEMM, double-buffered (out projection) ----------------
template<typename OUT>
__device__ __forceinline__ void gemm_bt_128db(const bf16_t* __restrict__ A,
                                              const bf16_t* __restrict__ W,
                                              OUT* __restrict__ C,
                                              int Kdim, int ldc_n, int brow, int bcol) {
  __shared__ __align__(16) bf16_t As[2][128 * 32];
  __shared__ __align__(16) bf16_t Bs[2][128 * 32];
  const int lane = threadIdx.x & 63;
  const int w    = threadIdx.x >> 6;
  const int lo   = lane & 15, hi = lane >> 4;
  const int wr   = w >> 1, wc = w & 1;

  f32x4 acc[4][4];
  #pragma unroll
  for (int i = 0; i < 4; ++i)
    #pragma unroll
    for (int j = 0; j < 4; ++j) acc[i][j] = (f32x4){0.f, 0.f, 0.f, 0.f};

#define GSTAGE(BUF, KT)                                                        \
  {                                                                            \
    _Pragma("unroll")                                                          \
    for (int i = 0; i < 2; ++i) {                                              \
      int chunk = w * 2 + i;                                                   \
      int r = chunk * 16 + (lane >> 2);                                        \
      int c = (lane & 3) * 8;                                                  \
      async16(A + (size_t)(brow + r) * Kdim + (KT) + c,                        \
              (char*)As[BUF] + chunk * 1024);                                  \
      async16(W + (size_t)(bcol + r) * Kdim + (KT) + c,                        \
              (char*)Bs[BUF] + chunk * 1024);                                  \
    }                                                                          \
  }

  const int nK = Kdim >> 5;
  GSTAGE(0, 0)
  int cur = 0;
  for (int ki = 0; ki < nK; ++ki) {
    if (ki + 1 < nK) {
      GSTAGE(cur ^ 1, (ki + 1) * 32)
      asm volatile("s_waitcnt vmcnt(4)" ::: "memory");
    } else {
      asm volatile("s_waitcnt vmcnt(0)" ::: "memory");
    }
    __builtin_amdgcn_s_barrier();
    bf16x8 af[4], bfr[4];
    #pragma unroll
    for (int mi = 0; mi < 4; ++mi)
      af[mi] = *(const bf16x8*)&As[cur][(wr * 64 + mi * 16 + lo) * 32 + hi * 8];
    #pragma unroll
    for (int ni = 0; ni < 4; ++ni)
      bfr[ni] = *(const bf16x8*)&Bs[cur][(wc * 64 + ni * 16 + lo) * 32 + hi * 8];
    #pragma unroll
    for (int mi = 0; mi < 4; ++mi)
      #pragma unroll
      for (int ni = 0; ni < 4; ++ni)
        acc[mi][ni] = MFMA16(af[mi], bfr[ni], acc[mi][ni]);
    __builtin_amdgcn_s_barrier();
    cur ^= 1;
  }
#undef GSTAGE

  #pragma unroll
  for (int mi = 0; mi < 4; ++mi)
    #pragma unroll
    for (int ni = 0; ni < 4; ++ni)
      #pragma unroll
      for (int i = 0; i < 4; ++i) {
        int row = brow + wr * 64 + mi * 16 + hi * 4 + i;
        int col = bcol + wc * 64 + ni * 16 + lo;
        C[(size_t)row * ldc_n + col] = (OUT)acc[mi][ni][i];
      }
}

__global__ __launch_bounds__(256) void out_gemm_k(const bf16_t* __restrict__ O,
                                                  const bf16_t* __restrict__ wob,
                                                  float* __restrict__ Y) {
  gemm_bt_128db<float>(O, wob, Y, D_, D_, blockIdx.x * 128, blockIdx.y * 128);
}

// ---------------- V transpose: V(B,T,D) -> Vt[(b*H+h)*64+dh][T] ----------------
__global__ __launch_bounds__(256) void vt_k(const bf16_t* __restrict__ V,
                                            bf16_t* __restrict__ Vt) {
  __shared__ bf16_t Tl[64][68];
  const int t0 = blockIdx.x * 64;
  const int bh = blockIdx.y, b = bh >> 4, h = bh & 15;
  const int tid = threadIdx.x;
  #pragma unroll
  for (int it = 0; it < 2; ++it) {
    int idx = it * 256 + tid;
    int r = idx >> 3, c8 = (idx & 7) * 8;
    *(bf16x8*)&Tl[r][c8] = *(const bf16x8*)&V[((size_t)(b * T_ + t0 + r)) * D_ + h * 64 + c8];
  }
  __syncthreads();
  #pragma unroll
  for (int it = 0; it < 2; ++it) {
    int idx = it * 256 + tid;
    int dh = idx >> 3, tc = (idx & 7) * 8;
    bf16x8 v;
    #pragma unroll
    for (int j = 0; j < 8; ++j) v[j] = Tl[tc + j][dh];
    *(bf16x8*)&Vt[((size_t)bh * 64 + dh) * T_ + t0 + tc] = v;
  }
}

// ---------------- flash attention: r10 structure (measured 41.8us) ----------------
__global__ __launch_bounds__(512) void attn_k(const bf16_t* __restrict__ Q,
                                              const bf16_t* __restrict__ K,
                                              const bf16_t* __restrict__ Vt,
                                              bf16_t* __restrict__ O) {
  const int bh = blockIdx.x, b = bh >> 4, h = bh & 15;
  const int yy = (int)blockIdx.y;
  const int qt = (yy < 8) ? (15 - 2 * yy) : (30 - 2 * yy);
  const int tid = threadIdx.x;

  __shared__ __align__(16) char smem[65536];

  const bf16_t* Kt0 = K + ((size_t)b * T_) * D_ + h * 64;
  const bf16_t* Vt0 = Vt + (size_t)bh * 64 * T_;

  const int lane = tid & 63, w = tid >> 6;
  const int wl = w & 3, wg = w >> 2;
  const int ln = lane & 31, hi = lane >> 5;
  const int tl = tid & 255;
  const int tau = (ln & ~12) | (((ln & 4) << 1) | ((ln & 8) >> 1));
  char* sgbase = smem + ((tid >= 256) ? 32768 : 0);
  char* cgbase = smem + wg * 32768;
  float* mo = (float*)smem;
  float* ml = (float*)(smem + 33792);

  const int q_abs = qt * 128 + wl * 32 + ln;
  bf16x8 qf[4];
  {
    const bf16_t* Qrow = Q + ((size_t)b * T_ + q_abs) * D_ + h * 64;
    #pragma unroll
    for (int ks = 0; ks < 4; ++ks)
      qf[ks] = *(const bf16x8*)(Qrow + ks * 16 + hi * 8);
  }

  f32x16 o0 = zero16(), o1 = zero16();
  float m = -1e30f, l = 0.f;

  const int jc    = qt + 1;
  const int jd    = 2 * qt + (wl >> 1);
  const int tbase = wg ? (qt + 1) : 0;

#define STAGE8(BUF, TT)                                                       \
  {                                                                           \
    char* kd = sgbase + (BUF) * 8192;                                         \
    char* vd = sgbase + 16384 + (BUF) * 8192;                                 \
    _Pragma("unroll")                                                         \
    for (int it = 0; it < 2; ++it) {                                          \
      int c = it * 256 + tl;                                                  \
      int row = c >> 3, sl = c & 7;                                           \
      int slg = sl ^ (row & 7);                                               \
      async16(Kt0 + ((size_t)((TT) * 64 + row)) * D_ + slg * 8, kd + c * 16); \
      async16(Vt0 + (size_t)row * T_ + (TT) * 64 + slg * 8, vd + c * 16);     \
    }                                                                         \
  }

#define PACK_PV8(PS, KS, VB)                                                  \
  {                                                                           \
    const int r0 = ((KS) & 1) * 8;                                            \
    u32x4 pw = {pk2((PS)[r0 + 0], (PS)[r0 + 1]),                              \
                pk2((PS)[r0 + 2], (PS)[r0 + 3]),                              \
                pk2((PS)[r0 + 4], (PS)[r0 + 5]),                              \
                pk2((PS)[r0 + 6], (PS)[r0 + 7])};                             \
    bf16x8 pb = __builtin_bit_cast(bf16x8, pw);                               \
    const int sg = (KS) * 2 + hi;                                             \
    int row = ln;                                                             \
    bf16x8 vf0 = *(const bf16x8*)((VB) + row * 64 + ((sg ^ (row & 7)) * 8));  \
    o0 = MFMA32(vf0, pb, o0);                                                 \
    row = 32 + ln;                                                            \
    bf16x8 vf1 = *(const bf16x8*)((VB) + row * 64 + ((sg ^ (row & 7)) * 8));  \
    o1 = MFMA32(vf1, pb, o1);                                                 \
  }

  STAGE8(0, tbase)
  int cur = 0;
  for (int j = 0; j < jc; ++j) {
    if (j + 1 < jc) {
      STAGE8(cur ^ 1, tbase + j + 1)
      asm volatile("s_waitcnt vmcnt(4)" ::: "memory");
    } else {
      asm volatile("s_waitcnt vmcnt(0)" ::: "memory");
    }
    __builtin_amdgcn_s_barrier();

    const int tt = tbase + j;
    if (tt <= jd) {
      const bf16_t* Kb = (const bf16_t*)(cgbase + cur * 8192);
      const bf16_t* Vb = (const bf16_t*)(cgbase + 16384 + cur * 8192);
      f32x16 s0 = zero16(), s1 = zero16();
      __builtin_amdgcn_s_setprio(1);
      #pragma unroll
      for (int ks = 0; ks < 4; ++ks) {
        const int sg = ks * 2 + hi;
        int row = tau;
        bf16x8 kf0 = *(const bf16x8*)(Kb + row * 64 + ((sg ^ (row & 7)) * 8));
        s0 = MFMA32(kf0, qf[ks], s0);
        row = 32 + tau;
        bf16x8 kf1 = *(const bf16x8*)(Kb + row * 64 + ((sg ^ (row & 7)) * 8));
        s1 = MFMA32(kf1, qf[ks], s1);
      }
      __builtin_amdgcn_s_setprio(0);
      if (tt == jd) {
        const int kv0 = tt * 64;
        #pragma unroll
        for (int r = 0; r < 16; ++r) {
          const int pos = (r & 7) + 16 * (r >> 3) + 8 * hi;
          if (kv0 + pos      > q_abs) s0[r] = -3e38f;
          if (kv0 + 32 + pos > q_abs) s1[r] = -3e38f;
        }
      }
      float t[16];
      #pragma unroll
      for (int r = 0; r < 16; ++r) t[r] = fmaxf(s0[r], s1[r]);
      #pragma unroll
      for (int st = 8; st >= 1; st >>= 1)
        #pragma unroll
        for (int i = 0; i < st; ++i) t[i] = fmaxf(t[i], t[i + st]);
      float pmax = xswap_max(t[0]);
      if (!__all(pmax - m <= DEFER_THR)) {
        float mn   = fmaxf(m, pmax);
        float corr = EXP2(m - mn);
        m = mn;
        l *= corr;
        #pragma unroll
        for (int r = 0; r < 16; ++r) { o0[r] *= corr; o1[r] *= corr; }
      }
      float u[16];
      #pragma unroll
      for (int r = 0; r < 16; ++r) {
        float p0 = EXP2(s0[r] - m); s0[r] = p0;
        float p1 = EXP2(s1[r] - m); s1[r] = p1;
        u[r] = p0 + p1;
      }
      #pragma unroll
      for (int st = 8; st >= 1; st >>= 1)
        #pragma unroll
        for (int i = 0; i < st; ++i) u[i] += u[i + st];
      l += xswap_sum(u[0]);
      __builtin_amdgcn_s_setprio(1);
      PACK_PV8(s0, 0, Vb)
      PACK_PV8(s0, 1, Vb)
      PACK_PV8(s1, 2, Vb)
      PACK_PV8(s1, 3, Vb)
      __builtin_amdgcn_s_setprio(0);
    }
    __builtin_amdgcn_s_barrier();
    cur ^= 1;
  }

  if (wg == 1) {
    float* mop = mo + ((size_t)wl * 64 + lane) * 33;
    #pragma unroll
    for (int r = 0; r < 16; ++r) { mop[r] = o0[r]; mop[16 + r] = o1[r]; }
    float* mlp = ml + ((size_t)wl * 64 + lane) * 2;
    mlp[0] = m; mlp[1] = l;
  }
  __syncthreads();
  if (wg == 0) {
    const float* mop = mo + ((size_t)wl * 64 + lane) * 33;
    const float* mlp = ml + ((size_t)wl * 64 + lane) * 2;
    float mB = mlp[0], lB = mlp[1];
    float mS = fmaxf(m, mB);
    float cA = EXP2(m - mS), cB = EXP2(mB - mS);
    float lS = l * cA + lB * cB;
    float rl = 1.0f / lS;
    bf16_t* Orow = O + ((size_t)b * T_ + q_abs) * D_ + h * 64;
    #pragma unroll
    for (int g = 0; g < 4; ++g) {
      const int dh0 = 8 * g + 4 * hi;
      bf16x4 v0, v1;
      #pragma unroll
      for (int jj = 0; jj < 4; ++jj) {
        v0[jj] = (__bf16)((o0[4 * g + jj] * cA + mop[4 * g + jj] * cB) * rl);
        v1[jj] = (__bf16)((o1[4 * g + jj] * cA + mop[16 + 4 * g + jj] * cB) * rl);
      }
      *(bf16x4*)(Orow + dh0)      = v0;
      *(bf16x4*)(Orow + 32 + dh0) = v1;
    }
  }
#undef STAGE8
#undef PACK_PV8
}

// ---------------- launcher ----------------
extern "C" void kernel_launch(void* const* d_in, const int* in_sizes, int n_in,
                              void* d_out, int out_size, void* d_ws, size_t ws_size,
                              hipStream_t stream) {
  const float* x  = (const float*)d_in[0];
  const float* wq = (const float*)d_in[1];
  const float* wk = (const float*)d_in[2];
  const float* wv = (const float*)d_in[3];
  const float* wo = (const float*)d_in[4];
  float* out = (float*)d_out;

  char* ws = (char*)d_ws;
  bf16_t* xb  = (bf16_t*)(ws);                       // 8 MB
  bf16_t* wqb = (bf16_t*)(ws + (size_t)( 8 << 20));  // 2 MB each (contiguous qkv+o)
  bf16_t* wob = (bf16_t*)(ws + (size_t)(14 << 20));
  bf16_t* Qb  = (bf16_t*)(ws + (size_t)(16 << 20));  // 8 MB each, Q/K/V contiguous
  bf16_t* Kb  = (bf16_t*)(ws + (size_t)(24 << 20));
  bf16_t* Vb  = (bf16_t*)(ws + (size_t)(32 << 20));
  bf16_t* Vtb = (bf16_t*)(ws + (size_t)(40 << 20));
  bf16_t* Ob  = Vb;   // Vb dead after vt_k

  (void)in_sizes; (void)n_in; (void)out_size; (void)ws_size;

  hipFuncSetAttribute((const void*)qkv8_k,
                      hipFuncAttributeMaxDynamicSharedMemorySize, 131072);

  cast_all_k<<<dim3(4096), 256, 0, stream>>>(x, wq, wk, wv, wo, xb, wqb);
  qkv8_k<<<dim3(M_ / 256, D_ / 256, 3), 512, 131072, stream>>>(xb, wqb, Qb);
  vt_k<<<dim3(T_ / 64, B_ * H_), 256, 0, stream>>>(Vb, Vtb);
  attn_k<<<dim3(B_ * H_, T_ / 128), 512, 0, stream>>>(Qb, Kb, Vtb, Ob);
  out_gemm_k<<<dim3(M_ / 128, D_ / 128), 256, 0, stream>>>(Ob, wob, out);
}